// Round 1
// baseline (1150.580 us; speedup 1.0000x reference)
//
#include <hip/hip_runtime.h>

#define N_NODES 100000
#define N_EDGES 600000
#define D 128

// ---------------------------------------------------------------------------
// Scatter: for each edge (src -> tgt), seg_sum[tgt] += node_feature[src],
// cnt[tgt] += 1. 32 threads per edge, 4 floats per thread (float4 gather).
// ---------------------------------------------------------------------------
__global__ __launch_bounds__(256) void sage_scatter(
        const float* __restrict__ nf,
        const int* __restrict__ edges,
        float* __restrict__ seg_sum,
        unsigned int* __restrict__ cnt) {
    long long tid = (long long)blockIdx.x * blockDim.x + threadIdx.x;
    int e = (int)(tid >> 5);
    int l = (int)(tid & 31);
    if (e >= N_EDGES) return;
    int src = edges[e];
    int tgt = edges[N_EDGES + e];
    const float4 v = *reinterpret_cast<const float4*>(nf + (size_t)src * D + l * 4);
    float* dst = seg_sum + (size_t)tgt * D + l * 4;
    atomicAdd(dst + 0, v.x);
    atomicAdd(dst + 1, v.y);
    atomicAdd(dst + 2, v.z);
    atomicAdd(dst + 3, v.w);
    if (l == 0) atomicAdd(cnt + tgt, 1u);
}

// ---------------------------------------------------------------------------
// Fused GEMM: out[i][j] = sum_k A[i][k]*Wc[j][k] + bl[j] + bs[j]
//   A[i][k] = seg_sum[i][k]*inv_c[i]  (k < 128)
//           = node_feature[i][k-128]  (k >= 128)
//   Wc[j][k] = W_line[j][k] (k<128) else W_self[j][k-128]
// BM=64 rows/block, BK=64, 256 threads = 16x16, each thread 4 rows x 8 cols.
// ---------------------------------------------------------------------------
#define BM 64
#define BK 64

__global__ __launch_bounds__(256) void sage_gemm(
        const float* __restrict__ seg_sum,
        const unsigned int* __restrict__ cnt,
        const float* __restrict__ nf,
        const float* __restrict__ Wl,
        const float* __restrict__ Ws,
        const float* __restrict__ bl,
        const float* __restrict__ bs,
        float* __restrict__ out) {
    __shared__ float As[BK][BM + 1];   // As[kk][row]
    __shared__ float Bs[BK][D];        // Bs[kk][j]

    const int tid = threadIdx.x;
    const int tx = tid & 15;           // 0..15 -> 8 output cols each
    const int ty = tid >> 4;           // 0..15 -> 4 output rows each
    const int row0 = blockIdx.x * BM;

    float acc[4][8];
#pragma unroll
    for (int m = 0; m < 4; ++m)
#pragma unroll
        for (int n = 0; n < 8; ++n) acc[m][n] = 0.0f;

    // staging maps
    const int a_row = tid >> 2;         // 0..63
    const int a_kc  = (tid & 3) * 16;   // 0,16,32,48
    const int w_j   = tid >> 1;         // 0..127
    const int w_kc  = (tid & 1) * 32;   // 0 or 32

    const int grow = row0 + a_row;
    float inv_c = 1.0f;
    if (grow < N_NODES) {
        unsigned int c = cnt[grow];
        inv_c = 1.0f / (float)(c > 0u ? c : 1u);
    }

    for (int k0 = 0; k0 < 2 * D; k0 += BK) {
        // ---- stage A tile (transposed into LDS) ----
#pragma unroll
        for (int j = 0; j < 16; j += 4) {
            const int k = k0 + a_kc + j;
            float4 v = make_float4(0.f, 0.f, 0.f, 0.f);
            if (grow < N_NODES) {
                if (k < D) {
                    v = *reinterpret_cast<const float4*>(seg_sum + (size_t)grow * D + k);
                    v.x *= inv_c; v.y *= inv_c; v.z *= inv_c; v.w *= inv_c;
                } else {
                    v = *reinterpret_cast<const float4*>(nf + (size_t)grow * D + (k - D));
                }
            }
            As[a_kc + j + 0][a_row] = v.x;
            As[a_kc + j + 1][a_row] = v.y;
            As[a_kc + j + 2][a_row] = v.z;
            As[a_kc + j + 3][a_row] = v.w;
        }
        // ---- stage W tile ----
#pragma unroll
        for (int j = 0; j < 32; j += 4) {
            const int k = k0 + w_kc + j;
            const float* wsrc = (k < D) ? (Wl + (size_t)w_j * D + k)
                                        : (Ws + (size_t)w_j * D + (k - D));
            const float4 v = *reinterpret_cast<const float4*>(wsrc);
            Bs[w_kc + j + 0][w_j] = v.x;
            Bs[w_kc + j + 1][w_j] = v.y;
            Bs[w_kc + j + 2][w_j] = v.z;
            Bs[w_kc + j + 3][w_j] = v.w;
        }
        __syncthreads();

        // ---- compute ----
#pragma unroll
        for (int kk = 0; kk < BK; ++kk) {
            float a0 = As[kk][ty * 4 + 0];
            float a1 = As[kk][ty * 4 + 1];
            float a2 = As[kk][ty * 4 + 2];
            float a3 = As[kk][ty * 4 + 3];
            const float4 b0 = *reinterpret_cast<const float4*>(&Bs[kk][tx * 8]);
            const float4 b1 = *reinterpret_cast<const float4*>(&Bs[kk][tx * 8 + 4]);
            const float bv[8] = {b0.x, b0.y, b0.z, b0.w, b1.x, b1.y, b1.z, b1.w};
            const float av[4] = {a0, a1, a2, a3};
#pragma unroll
            for (int m = 0; m < 4; ++m)
#pragma unroll
                for (int n = 0; n < 8; ++n)
                    acc[m][n] = fmaf(av[m], bv[n], acc[m][n]);
        }
        __syncthreads();
    }

    // ---- epilogue: bias + store ----
    const float4 blv0 = *reinterpret_cast<const float4*>(bl + tx * 8);
    const float4 blv1 = *reinterpret_cast<const float4*>(bl + tx * 8 + 4);
    const float4 bsv0 = *reinterpret_cast<const float4*>(bs + tx * 8);
    const float4 bsv1 = *reinterpret_cast<const float4*>(bs + tx * 8 + 4);
    const float bias[8] = {blv0.x + bsv0.x, blv0.y + bsv0.y, blv0.z + bsv0.z, blv0.w + bsv0.w,
                           blv1.x + bsv1.x, blv1.y + bsv1.y, blv1.z + bsv1.z, blv1.w + bsv1.w};

#pragma unroll
    for (int m = 0; m < 4; ++m) {
        const int row = row0 + ty * 4 + m;
        if (row < N_NODES) {
            float4 o0, o1;
            o0.x = acc[m][0] + bias[0]; o0.y = acc[m][1] + bias[1];
            o0.z = acc[m][2] + bias[2]; o0.w = acc[m][3] + bias[3];
            o1.x = acc[m][4] + bias[4]; o1.y = acc[m][5] + bias[5];
            o1.z = acc[m][6] + bias[6]; o1.w = acc[m][7] + bias[7];
            *reinterpret_cast<float4*>(out + (size_t)row * D + tx * 8) = o0;
            *reinterpret_cast<float4*>(out + (size_t)row * D + tx * 8 + 4) = o1;
        }
    }
}

extern "C" void kernel_launch(void* const* d_in, const int* in_sizes, int n_in,
                              void* d_out, int out_size, void* d_ws, size_t ws_size,
                              hipStream_t stream) {
    const float* nf    = (const float*)d_in[0];
    const int*   edges = (const int*)d_in[1];
    const float* Wl    = (const float*)d_in[2];
    const float* bl    = (const float*)d_in[3];
    const float* Ws    = (const float*)d_in[4];
    const float* bs    = (const float*)d_in[5];
    float* out = (float*)d_out;

    float* seg_sum = (float*)d_ws;
    unsigned int* cnt = (unsigned int*)((char*)d_ws + (size_t)N_NODES * D * sizeof(float));

    // zero seg_sum + cnt
    hipMemsetAsync(d_ws, 0, (size_t)N_NODES * D * sizeof(float) + N_NODES * sizeof(unsigned int),
                   stream);

    // scatter
    {
        const long long total = (long long)N_EDGES * 32;
        const int blocks = (int)((total + 255) / 256);
        sage_scatter<<<blocks, 256, 0, stream>>>(nf, edges, seg_sum, cnt);
    }

    // fused GEMM
    {
        const int blocks = (N_NODES + BM - 1) / BM;
        sage_gemm<<<blocks, 256, 0, stream>>>(seg_sum, cnt, nf, Wl, Ws, bl, bs, out);
    }
}

// Round 2
// 236.527 us; speedup vs baseline: 4.8645x; 4.8645x over previous
//
#include <hip/hip_runtime.h>

#define N_NODES 100000
#define N_EDGES 600000
#define D 128

#define SCAN_CHUNK 512
#define SCAN_NBLK ((N_NODES + SCAN_CHUNK - 1) / SCAN_CHUNK)   // 196

// ---------------------------------------------------------------------------
// Phase A: degree histogram
// ---------------------------------------------------------------------------
__global__ __launch_bounds__(256) void k_hist(
        const int* __restrict__ edges, unsigned int* __restrict__ deg) {
    int e = blockIdx.x * blockDim.x + threadIdx.x;
    if (e >= N_EDGES) return;
    atomicAdd(&deg[edges[N_EDGES + e]], 1u);
}

// ---------------------------------------------------------------------------
// Phase B1: per-chunk sums (chunk = 512 degrees, 256 threads)
// ---------------------------------------------------------------------------
__global__ __launch_bounds__(256) void k_scan1(
        const unsigned int* __restrict__ deg, unsigned int* __restrict__ partials) {
    __shared__ unsigned int s[256];
    const int t = threadIdx.x;
    const int base = blockIdx.x * SCAN_CHUNK;
    unsigned int v = 0;
    int i0 = base + t, i1 = base + 256 + t;
    if (i0 < N_NODES) v += deg[i0];
    if (i1 < N_NODES) v += deg[i1];
    s[t] = v;
    __syncthreads();
    for (int d = 128; d > 0; d >>= 1) {
        if (t < d) s[t] += s[t + d];
        __syncthreads();
    }
    if (t == 0) partials[blockIdx.x] = s[0];
}

// ---------------------------------------------------------------------------
// Phase B2: exclusive scan of the 196 partials (single block, Hillis-Steele)
// ---------------------------------------------------------------------------
__global__ __launch_bounds__(256) void k_scan2(unsigned int* __restrict__ partials) {
    __shared__ unsigned int s[256];
    const int t = threadIdx.x;
    s[t] = (t < SCAN_NBLK) ? partials[t] : 0u;
    __syncthreads();
    for (int d = 1; d < 256; d <<= 1) {
        unsigned int add = (t >= d) ? s[t - d] : 0u;
        __syncthreads();
        s[t] += add;
        __syncthreads();
    }
    if (t < SCAN_NBLK) partials[t] = (t > 0) ? s[t - 1] : 0u;   // exclusive
}

// ---------------------------------------------------------------------------
// Phase B3: per-chunk exclusive scan + base; write off[] and cursor[]
// ---------------------------------------------------------------------------
__global__ __launch_bounds__(256) void k_scan3(
        const unsigned int* __restrict__ deg, const unsigned int* __restrict__ partials,
        unsigned int* __restrict__ off, unsigned int* __restrict__ cursor) {
    __shared__ unsigned int pair[256];
    const int t = threadIdx.x;
    const int i0 = blockIdx.x * SCAN_CHUNK + 2 * t;
    const int i1 = i0 + 1;
    unsigned int e0 = (i0 < N_NODES) ? deg[i0] : 0u;
    unsigned int e1 = (i1 < N_NODES) ? deg[i1] : 0u;
    pair[t] = e0 + e1;
    __syncthreads();
    for (int d = 1; d < 256; d <<= 1) {
        unsigned int add = (t >= d) ? pair[t - d] : 0u;
        __syncthreads();
        pair[t] += add;
        __syncthreads();
    }
    unsigned int base = partials[blockIdx.x] + ((t > 0) ? pair[t - 1] : 0u);
    if (i0 < N_NODES) { off[i0] = base;      cursor[i0] = base; }
    if (i1 < N_NODES) { off[i1] = base + e0; cursor[i1] = base + e0; }
}

// ---------------------------------------------------------------------------
// Phase C: bucket-fill sorted source indices
// ---------------------------------------------------------------------------
__global__ __launch_bounds__(256) void k_fill(
        const int* __restrict__ edges, unsigned int* __restrict__ cursor,
        unsigned int* __restrict__ sorted_src) {
    int e = blockIdx.x * blockDim.x + threadIdx.x;
    if (e >= N_EDGES) return;
    int src = edges[e];
    int tgt = edges[N_EDGES + e];
    unsigned int p = atomicAdd(&cursor[tgt], 1u);
    sorted_src[p] = (unsigned int)src;
}

// ---------------------------------------------------------------------------
// Phase D: gather-mean. One wave per node; lane l owns cols [2l, 2l+1].
// ---------------------------------------------------------------------------
__global__ __launch_bounds__(256) void k_gather(
        const float* __restrict__ nf, const unsigned int* __restrict__ off,
        const unsigned int* __restrict__ deg, const unsigned int* __restrict__ sorted_src,
        float* __restrict__ mean) {
    const int wave = threadIdx.x >> 6;
    const int lane = threadIdx.x & 63;
    const int node = blockIdx.x * 4 + wave;
    if (node >= N_NODES) return;
    const unsigned int d = deg[node];
    const unsigned int o = off[node];
    const float2* __restrict__ nf2 = reinterpret_cast<const float2*>(nf);
    float ax = 0.f, ay = 0.f;
    unsigned int j = 0;
    for (; j + 2 <= d; j += 2) {
        unsigned int s0 = sorted_src[o + j];
        unsigned int s1 = sorted_src[o + j + 1];
        float2 v0 = nf2[(size_t)s0 * 64 + lane];
        float2 v1 = nf2[(size_t)s1 * 64 + lane];
        ax += v0.x + v1.x;
        ay += v0.y + v1.y;
    }
    if (j < d) {
        unsigned int s0 = sorted_src[o + j];
        float2 v0 = nf2[(size_t)s0 * 64 + lane];
        ax += v0.x;
        ay += v0.y;
    }
    const float inv = 1.0f / (float)(d > 0u ? d : 1u);
    float2 r; r.x = ax * inv; r.y = ay * inv;
    reinterpret_cast<float2*>(mean)[(size_t)node * 64 + lane] = r;
}

// ---------------------------------------------------------------------------
// Fused GEMM: out[i][j] = sum_k A[i][k]*Wc[j][k] + bl[j] + bs[j]
//   A[i][k] = mean[i][k] (k<128) else node_feature[i][k-128]
//   Wc[j][k] = W_line[j][k] (k<128) else W_self[j][k-128]
// ---------------------------------------------------------------------------
#define BM 64
#define BK 64

__global__ __launch_bounds__(256) void sage_gemm(
        const float* __restrict__ mean,
        const float* __restrict__ nf,
        const float* __restrict__ Wl,
        const float* __restrict__ Ws,
        const float* __restrict__ bl,
        const float* __restrict__ bs,
        float* __restrict__ out) {
    __shared__ float As[BK][BM + 1];   // As[kk][row]
    __shared__ float Bs[BK][D];        // Bs[kk][j]

    const int tid = threadIdx.x;
    const int tx = tid & 15;           // 8 output cols each
    const int ty = tid >> 4;           // 4 output rows each
    const int row0 = blockIdx.x * BM;

    float acc[4][8];
#pragma unroll
    for (int m = 0; m < 4; ++m)
#pragma unroll
        for (int n = 0; n < 8; ++n) acc[m][n] = 0.0f;

    const int a_row = tid >> 2;
    const int a_kc  = (tid & 3) * 16;
    const int w_j   = tid >> 1;
    const int w_kc  = (tid & 1) * 32;
    const int grow  = row0 + a_row;

    for (int k0 = 0; k0 < 2 * D; k0 += BK) {
#pragma unroll
        for (int j = 0; j < 16; j += 4) {
            const int k = k0 + a_kc + j;
            float4 v = make_float4(0.f, 0.f, 0.f, 0.f);
            if (grow < N_NODES) {
                const float* asrc = (k < D) ? (mean + (size_t)grow * D + k)
                                            : (nf + (size_t)grow * D + (k - D));
                v = *reinterpret_cast<const float4*>(asrc);
            }
            As[a_kc + j + 0][a_row] = v.x;
            As[a_kc + j + 1][a_row] = v.y;
            As[a_kc + j + 2][a_row] = v.z;
            As[a_kc + j + 3][a_row] = v.w;
        }
#pragma unroll
        for (int j = 0; j < 32; j += 4) {
            const int k = k0 + w_kc + j;
            const float* wsrc = (k < D) ? (Wl + (size_t)w_j * D + k)
                                        : (Ws + (size_t)w_j * D + (k - D));
            const float4 v = *reinterpret_cast<const float4*>(wsrc);
            Bs[w_kc + j + 0][w_j] = v.x;
            Bs[w_kc + j + 1][w_j] = v.y;
            Bs[w_kc + j + 2][w_j] = v.z;
            Bs[w_kc + j + 3][w_j] = v.w;
        }
        __syncthreads();

#pragma unroll
        for (int kk = 0; kk < BK; ++kk) {
            const float av[4] = {As[kk][ty * 4 + 0], As[kk][ty * 4 + 1],
                                 As[kk][ty * 4 + 2], As[kk][ty * 4 + 3]};
            const float4 b0 = *reinterpret_cast<const float4*>(&Bs[kk][tx * 8]);
            const float4 b1 = *reinterpret_cast<const float4*>(&Bs[kk][tx * 8 + 4]);
            const float bv[8] = {b0.x, b0.y, b0.z, b0.w, b1.x, b1.y, b1.z, b1.w};
#pragma unroll
            for (int m = 0; m < 4; ++m)
#pragma unroll
                for (int n = 0; n < 8; ++n)
                    acc[m][n] = fmaf(av[m], bv[n], acc[m][n]);
        }
        __syncthreads();
    }

    const float4 blv0 = *reinterpret_cast<const float4*>(bl + tx * 8);
    const float4 blv1 = *reinterpret_cast<const float4*>(bl + tx * 8 + 4);
    const float4 bsv0 = *reinterpret_cast<const float4*>(bs + tx * 8);
    const float4 bsv1 = *reinterpret_cast<const float4*>(bs + tx * 8 + 4);
    const float bias[8] = {blv0.x + bsv0.x, blv0.y + bsv0.y, blv0.z + bsv0.z, blv0.w + bsv0.w,
                           blv1.x + bsv1.x, blv1.y + bsv1.y, blv1.z + bsv1.z, blv1.w + bsv1.w};

#pragma unroll
    for (int m = 0; m < 4; ++m) {
        const int row = row0 + ty * 4 + m;
        if (row < N_NODES) {
            float4 o0, o1;
            o0.x = acc[m][0] + bias[0]; o0.y = acc[m][1] + bias[1];
            o0.z = acc[m][2] + bias[2]; o0.w = acc[m][3] + bias[3];
            o1.x = acc[m][4] + bias[4]; o1.y = acc[m][5] + bias[5];
            o1.z = acc[m][6] + bias[6]; o1.w = acc[m][7] + bias[7];
            *reinterpret_cast<float4*>(out + (size_t)row * D + tx * 8) = o0;
            *reinterpret_cast<float4*>(out + (size_t)row * D + tx * 8 + 4) = o1;
        }
    }
}

extern "C" void kernel_launch(void* const* d_in, const int* in_sizes, int n_in,
                              void* d_out, int out_size, void* d_ws, size_t ws_size,
                              hipStream_t stream) {
    const float* nf    = (const float*)d_in[0];
    const int*   edges = (const int*)d_in[1];
    const float* Wl    = (const float*)d_in[2];
    const float* bl    = (const float*)d_in[3];
    const float* Ws    = (const float*)d_in[4];
    const float* bs    = (const float*)d_in[5];
    float* out = (float*)d_out;

    // workspace layout
    char* p = (char*)d_ws;
    float* mean = (float*)p;                  p += (size_t)N_NODES * D * sizeof(float);
    unsigned int* deg     = (unsigned int*)p; p += (size_t)N_NODES * sizeof(unsigned int);
    unsigned int* off     = (unsigned int*)p; p += (size_t)N_NODES * sizeof(unsigned int);
    unsigned int* cursor  = (unsigned int*)p; p += (size_t)N_NODES * sizeof(unsigned int);
    unsigned int* sorted_src = (unsigned int*)p; p += (size_t)N_EDGES * sizeof(unsigned int);
    unsigned int* partials   = (unsigned int*)p;

    // zero degree histogram only (mean is fully overwritten by k_gather)
    hipMemsetAsync(deg, 0, (size_t)N_NODES * sizeof(unsigned int), stream);

    k_hist<<<(N_EDGES + 255) / 256, 256, 0, stream>>>(edges, deg);
    k_scan1<<<SCAN_NBLK, 256, 0, stream>>>(deg, partials);
    k_scan2<<<1, 256, 0, stream>>>(partials);
    k_scan3<<<SCAN_NBLK, 256, 0, stream>>>(deg, partials, off, cursor);
    k_fill<<<(N_EDGES + 255) / 256, 256, 0, stream>>>(edges, cursor, sorted_src);
    k_gather<<<(N_NODES + 3) / 4, 256, 0, stream>>>(nf, off, deg, sorted_src, mean);
    sage_gemm<<<(N_NODES + BM - 1) / BM, 256, 0, stream>>>(mean, nf, Wl, Ws, bl, bs, out);
}

// Round 3
// 178.689 us; speedup vs baseline: 6.4390x; 1.3237x over previous
//
#include <hip/hip_runtime.h>

#define N_NODES 100000
#define N_EDGES 600000
#define D 128
#define M_PAD 100096            // 782 * 128

#define SCAN_CHUNK 512
#define SCAN_NBLK ((N_NODES + SCAN_CHUNK - 1) / SCAN_CHUNK)   // 196

typedef unsigned int uint32;
typedef __attribute__((ext_vector_type(8))) short short8;
typedef __attribute__((ext_vector_type(4))) float f32x4;

__device__ __forceinline__ uint32 f2bf(float x) {          // RNE f32 -> bf16
    uint32 u = __float_as_uint(x);
    return (u + 0x7FFFu + ((u >> 16) & 1u)) >> 16;
}
__device__ __forceinline__ float bflo(uint32 u) { return __uint_as_float(u << 16); }
__device__ __forceinline__ float bfhi(uint32 u) { return __uint_as_float(u & 0xFFFF0000u); }

// ---------------------------------------------------------------------------
// Convert nf (fp32) -> bf16 upper K-half of Abuf rows. 8 floats/thread.
// ---------------------------------------------------------------------------
__global__ __launch_bounds__(256) void k_convert(
        const float* __restrict__ nf, unsigned short* __restrict__ Abuf) {
    int idx = blockIdx.x * 256 + threadIdx.x;          // 0 .. 1.6M
    if (idx >= N_NODES * 16) return;
    int r = idx >> 4;
    int c = (idx & 15) * 8;
    const float4 v0 = *reinterpret_cast<const float4*>(nf + (size_t)r * D + c);
    const float4 v1 = *reinterpret_cast<const float4*>(nf + (size_t)r * D + c + 4);
    uint4 w;
    w.x = f2bf(v0.x) | (f2bf(v0.y) << 16);
    w.y = f2bf(v0.z) | (f2bf(v0.w) << 16);
    w.z = f2bf(v1.x) | (f2bf(v1.y) << 16);
    w.w = f2bf(v1.z) | (f2bf(v1.w) << 16);
    *reinterpret_cast<uint4*>(Abuf + (size_t)r * 256 + D + c) = w;
}

// ---------------------------------------------------------------------------
// Degree histogram
// ---------------------------------------------------------------------------
__global__ __launch_bounds__(256) void k_hist(
        const int* __restrict__ edges, uint32* __restrict__ deg) {
    int e = blockIdx.x * blockDim.x + threadIdx.x;
    if (e >= N_EDGES) return;
    atomicAdd(&deg[edges[N_EDGES + e]], 1u);
}

// ---------------------------------------------------------------------------
// Scan phase 1: per-chunk sums
// ---------------------------------------------------------------------------
__global__ __launch_bounds__(256) void k_scan1(
        const uint32* __restrict__ deg, uint32* __restrict__ partials) {
    __shared__ uint32 s[256];
    const int t = threadIdx.x;
    const int base = blockIdx.x * SCAN_CHUNK;
    uint32 v = 0;
    int i0 = base + t, i1 = base + 256 + t;
    if (i0 < N_NODES) v += deg[i0];
    if (i1 < N_NODES) v += deg[i1];
    s[t] = v;
    __syncthreads();
    for (int d = 128; d > 0; d >>= 1) {
        if (t < d) s[t] += s[t + d];
        __syncthreads();
    }
    if (t == 0) partials[blockIdx.x] = s[0];
}

// ---------------------------------------------------------------------------
// Scan phase 2: exclusive scan of partials (single block)
// ---------------------------------------------------------------------------
__global__ __launch_bounds__(256) void k_scan2(uint32* __restrict__ partials) {
    __shared__ uint32 s[256];
    const int t = threadIdx.x;
    s[t] = (t < SCAN_NBLK) ? partials[t] : 0u;
    __syncthreads();
    for (int d = 1; d < 256; d <<= 1) {
        uint32 add = (t >= d) ? s[t - d] : 0u;
        __syncthreads();
        s[t] += add;
        __syncthreads();
    }
    if (t < SCAN_NBLK) partials[t] = (t > 0) ? s[t - 1] : 0u;
}

// ---------------------------------------------------------------------------
// Scan phase 3: per-chunk exclusive scan + base -> off, cursor
// ---------------------------------------------------------------------------
__global__ __launch_bounds__(256) void k_scan3(
        const uint32* __restrict__ deg, const uint32* __restrict__ partials,
        uint32* __restrict__ off, uint32* __restrict__ cursor) {
    __shared__ uint32 pair[256];
    const int t = threadIdx.x;
    const int i0 = blockIdx.x * SCAN_CHUNK + 2 * t;
    const int i1 = i0 + 1;
    uint32 e0 = (i0 < N_NODES) ? deg[i0] : 0u;
    uint32 e1 = (i1 < N_NODES) ? deg[i1] : 0u;
    pair[t] = e0 + e1;
    __syncthreads();
    for (int d = 1; d < 256; d <<= 1) {
        uint32 add = (t >= d) ? pair[t - d] : 0u;
        __syncthreads();
        pair[t] += add;
        __syncthreads();
    }
    uint32 base = partials[blockIdx.x] + ((t > 0) ? pair[t - 1] : 0u);
    if (i0 < N_NODES) { off[i0] = base;      cursor[i0] = base; }
    if (i1 < N_NODES) { off[i1] = base + e0; cursor[i1] = base + e0; }
}

// ---------------------------------------------------------------------------
// Bucket-fill sorted source indices
// ---------------------------------------------------------------------------
__global__ __launch_bounds__(256) void k_fill(
        const int* __restrict__ edges, uint32* __restrict__ cursor,
        uint32* __restrict__ sorted_src) {
    int e = blockIdx.x * blockDim.x + threadIdx.x;
    if (e >= N_EDGES) return;
    int src = edges[e];
    int tgt = edges[N_EDGES + e];
    uint32 p = atomicAdd(&cursor[tgt], 1u);
    sorted_src[p] = (uint32)src;
}

// ---------------------------------------------------------------------------
// Fused weight prep: Wc[j][k] bf16 (k<128: W_line, else W_self), biasc = bl+bs
// ---------------------------------------------------------------------------
__global__ __launch_bounds__(256) void k_prep_w(
        const float* __restrict__ Wl, const float* __restrict__ Ws,
        const float* __restrict__ bl, const float* __restrict__ bs,
        unsigned short* __restrict__ Wc, float* __restrict__ biasc) {
    int t = blockIdx.x * 256 + threadIdx.x;
    if (t < D * 256) {
        int j = t >> 8, k = t & 255;
        float v = (k < D) ? Wl[(size_t)j * D + k] : Ws[(size_t)j * D + (k - D)];
        Wc[t] = (unsigned short)f2bf(v);
    }
    if (t < D) biasc[t] = bl[t] + bs[t];
}

// ---------------------------------------------------------------------------
// Gather-mean in bf16. One wave per node; lane owns 2 cols (uint = bf16x2).
// Reads nf-halves of Abuf, writes mean-half of Abuf (bf16, RNE).
// ---------------------------------------------------------------------------
__global__ __launch_bounds__(256) void k_gather(
        const unsigned short* __restrict__ AbufC,
        unsigned short* __restrict__ Abuf,
        const uint32* __restrict__ off, const uint32* __restrict__ deg,
        const uint32* __restrict__ sorted_src) {
    const int wave = threadIdx.x >> 6;
    const int lane = threadIdx.x & 63;
    const int node = blockIdx.x * 4 + wave;
    if (node >= N_NODES) return;
    const uint32 d = deg[node];
    const uint32 o = off[node];
    const uint32* __restrict__ src = sorted_src + o;
    float ax = 0.f, ay = 0.f;
    uint32 j = 0;
    for (; j + 2 <= d; j += 2) {
        uint32 s0 = src[j];
        uint32 s1 = src[j + 1];
        uint32 u0 = *reinterpret_cast<const uint32*>(AbufC + (size_t)s0 * 256 + D + lane * 2);
        uint32 u1 = *reinterpret_cast<const uint32*>(AbufC + (size_t)s1 * 256 + D + lane * 2);
        ax += bflo(u0) + bflo(u1);
        ay += bfhi(u0) + bfhi(u1);
    }
    if (j < d) {
        uint32 s0 = src[j];
        uint32 u0 = *reinterpret_cast<const uint32*>(AbufC + (size_t)s0 * 256 + D + lane * 2);
        ax += bflo(u0);
        ay += bfhi(u0);
    }
    const float inv = 1.0f / (float)(d > 0u ? d : 1u);
    uint32 packed = f2bf(ax * inv) | (f2bf(ay * inv) << 16);
    *reinterpret_cast<uint32*>(Abuf + (size_t)node * 256 + lane * 2) = packed;
}

// ---------------------------------------------------------------------------
// MFMA GEMM: out[i][j] = sum_k Abuf[i][k] * Wc[j][k] + biasc[j]
// 4 waves/block; wave = 32 rows x 128 cols = 2x8 fragments of 16x16, K=256.
// A-frag/B-frag: lane l holds row/col (l&15), k = (l>>4)*8 .. +8 (contiguous).
// No LDS, no barriers: B (64 KB) is L2-resident.
// ---------------------------------------------------------------------------
__global__ __launch_bounds__(256) void sage_mfma(
        const unsigned short* __restrict__ Abuf,
        const unsigned short* __restrict__ Wc,
        const float* __restrict__ biasc,
        float* __restrict__ out) {
    const int tid = threadIdx.x;
    const int wave = tid >> 6;
    const int lane = tid & 63;
    const int lr = lane & 15;              // fragment row/col
    const int lk = (lane >> 4) * 8;        // fragment k-offset
    const long long row0 = (long long)blockIdx.x * 128 + wave * 32;

    f32x4 acc[2][8];
#pragma unroll
    for (int m = 0; m < 2; ++m)
#pragma unroll
        for (int n = 0; n < 8; ++n) acc[m][n] = (f32x4){0.f, 0.f, 0.f, 0.f};

    const unsigned short* pa0 = Abuf + (row0 + lr) * 256 + lk;
    const unsigned short* pa1 = Abuf + (row0 + 16 + lr) * 256 + lk;
    const unsigned short* pb  = Wc + (size_t)lr * 256 + lk;

#pragma unroll
    for (int ks = 0; ks < 8; ++ks) {
        const int k = ks * 32;
        short8 a0 = *reinterpret_cast<const short8*>(pa0 + k);
        short8 a1 = *reinterpret_cast<const short8*>(pa1 + k);
#pragma unroll
        for (int n = 0; n < 8; ++n) {
            short8 b = *reinterpret_cast<const short8*>(pb + (size_t)n * 16 * 256 + k);
            acc[0][n] = __builtin_amdgcn_mfma_f32_16x16x32_bf16(a0, b, acc[0][n], 0, 0, 0);
            acc[1][n] = __builtin_amdgcn_mfma_f32_16x16x32_bf16(a1, b, acc[1][n], 0, 0, 0);
        }
    }

    // epilogue: bias + store (C/D: col = lane&15, row = (lane>>4)*4 + reg)
    float bv[8];
#pragma unroll
    for (int n = 0; n < 8; ++n) bv[n] = biasc[n * 16 + lr];

    const int rq = (lane >> 4) * 4;
#pragma unroll
    for (int m = 0; m < 2; ++m) {
#pragma unroll
        for (int r = 0; r < 4; ++r) {
            const long long row = row0 + m * 16 + rq + r;
            if (row < N_NODES) {
                float* orow = out + row * D;
#pragma unroll
                for (int n = 0; n < 8; ++n)
                    orow[n * 16 + lr] = acc[m][n][r] + bv[n];
            }
        }
    }
}

extern "C" void kernel_launch(void* const* d_in, const int* in_sizes, int n_in,
                              void* d_out, int out_size, void* d_ws, size_t ws_size,
                              hipStream_t stream) {
    const float* nf    = (const float*)d_in[0];
    const int*   edges = (const int*)d_in[1];
    const float* Wl    = (const float*)d_in[2];
    const float* bl    = (const float*)d_in[3];
    const float* Ws    = (const float*)d_in[4];
    const float* bs    = (const float*)d_in[5];
    float* out = (float*)d_out;

    // workspace layout
    char* p = (char*)d_ws;
    unsigned short* Abuf = (unsigned short*)p; p += (size_t)M_PAD * 256 * sizeof(unsigned short);
    uint32* deg        = (uint32*)p; p += (size_t)N_NODES * sizeof(uint32);
    uint32* off        = (uint32*)p; p += (size_t)N_NODES * sizeof(uint32);
    uint32* cursor     = (uint32*)p; p += (size_t)N_NODES * sizeof(uint32);
    uint32* sorted_src = (uint32*)p; p += (size_t)N_EDGES * sizeof(uint32);
    uint32* partials   = (uint32*)p; p += 1024;
    // Wc/biasc overlap the (dead-after-k_fill) cursor buffer
    unsigned short* Wc = (unsigned short*)cursor;              // 64 KB
    float* biasc       = (float*)(cursor + (D * 256) / 2);     // 512 B

    hipMemsetAsync(deg, 0, (size_t)N_NODES * sizeof(uint32), stream);

    k_convert<<<(N_NODES * 16 + 255) / 256, 256, 0, stream>>>(nf, Abuf);
    k_hist<<<(N_EDGES + 255) / 256, 256, 0, stream>>>(edges, deg);
    k_scan1<<<SCAN_NBLK, 256, 0, stream>>>(deg, partials);
    k_scan2<<<1, 256, 0, stream>>>(partials);
    k_scan3<<<SCAN_NBLK, 256, 0, stream>>>(deg, partials, off, cursor);
    k_fill<<<(N_EDGES + 255) / 256, 256, 0, stream>>>(edges, cursor, sorted_src);
    k_prep_w<<<(D * 256 + 255) / 256, 256, 0, stream>>>(Wl, Ws, bl, bs, Wc, biasc);
    k_gather<<<(N_NODES + 3) / 4, 256, 0, stream>>>(Abuf, Abuf, off, deg, sorted_src);
    sage_mfma<<<M_PAD / 128, 256, 0, stream>>>(Abuf, Wc, biasc, out);
}

// Round 4
// 169.446 us; speedup vs baseline: 6.7902x; 1.0545x over previous
//
#include <hip/hip_runtime.h>

#define N_NODES 100000
#define N_EDGES 600000
#define D 128
#define M_PAD 100096            // 782 * 128

#define SCAN_CHUNK 512
#define SCAN_NBLK ((N_NODES + SCAN_CHUNK - 1) / SCAN_CHUNK)   // 196

typedef unsigned int uint32;
typedef __attribute__((ext_vector_type(8))) short short8;
typedef __attribute__((ext_vector_type(4))) float f32x4;

__device__ __forceinline__ uint32 f2bf(float x) {          // RNE f32 -> bf16
    uint32 u = __float_as_uint(x);
    return (u + 0x7FFFu + ((u >> 16) & 1u)) >> 16;
}
__device__ __forceinline__ float bflo(uint32 u) { return __uint_as_float(u << 16); }
__device__ __forceinline__ float bfhi(uint32 u) { return __uint_as_float(u & 0xFFFF0000u); }

// ---------------------------------------------------------------------------
// Convert nf (fp32) -> bf16 upper K-half of Abuf rows. 8 floats/thread.
// ---------------------------------------------------------------------------
__global__ __launch_bounds__(256) void k_convert(
        const float* __restrict__ nf, unsigned short* __restrict__ Abuf) {
    int idx = blockIdx.x * 256 + threadIdx.x;          // 0 .. 1.6M
    if (idx >= N_NODES * 16) return;
    int r = idx >> 4;
    int c = (idx & 15) * 8;
    const float4 v0 = *reinterpret_cast<const float4*>(nf + (size_t)r * D + c);
    const float4 v1 = *reinterpret_cast<const float4*>(nf + (size_t)r * D + c + 4);
    uint4 w;
    w.x = f2bf(v0.x) | (f2bf(v0.y) << 16);
    w.y = f2bf(v0.z) | (f2bf(v0.w) << 16);
    w.z = f2bf(v1.x) | (f2bf(v1.y) << 16);
    w.w = f2bf(v1.z) | (f2bf(v1.w) << 16);
    *reinterpret_cast<uint4*>(Abuf + (size_t)r * 256 + D + c) = w;
}

// ---------------------------------------------------------------------------
// Degree histogram
// ---------------------------------------------------------------------------
__global__ __launch_bounds__(256) void k_hist(
        const int* __restrict__ edges, uint32* __restrict__ deg) {
    int e = blockIdx.x * blockDim.x + threadIdx.x;
    if (e >= N_EDGES) return;
    atomicAdd(&deg[edges[N_EDGES + e]], 1u);
}

// ---------------------------------------------------------------------------
// Scan phase 1: per-chunk sums
// ---------------------------------------------------------------------------
__global__ __launch_bounds__(256) void k_scan1(
        const uint32* __restrict__ deg, uint32* __restrict__ partials) {
    __shared__ uint32 s[256];
    const int t = threadIdx.x;
    const int base = blockIdx.x * SCAN_CHUNK;
    uint32 v = 0;
    int i0 = base + t, i1 = base + 256 + t;
    if (i0 < N_NODES) v += deg[i0];
    if (i1 < N_NODES) v += deg[i1];
    s[t] = v;
    __syncthreads();
    for (int d = 128; d > 0; d >>= 1) {
        if (t < d) s[t] += s[t + d];
        __syncthreads();
    }
    if (t == 0) partials[blockIdx.x] = s[0];
}

// ---------------------------------------------------------------------------
// Scan phase 2: exclusive scan of partials (single block)
// ---------------------------------------------------------------------------
__global__ __launch_bounds__(256) void k_scan2(uint32* __restrict__ partials) {
    __shared__ uint32 s[256];
    const int t = threadIdx.x;
    s[t] = (t < SCAN_NBLK) ? partials[t] : 0u;
    __syncthreads();
    for (int d = 1; d < 256; d <<= 1) {
        uint32 add = (t >= d) ? s[t - d] : 0u;
        __syncthreads();
        s[t] += add;
        __syncthreads();
    }
    if (t < SCAN_NBLK) partials[t] = (t > 0) ? s[t - 1] : 0u;
}

// ---------------------------------------------------------------------------
// Scan phase 3: per-chunk exclusive scan + base -> off, cursor
// ---------------------------------------------------------------------------
__global__ __launch_bounds__(256) void k_scan3(
        const uint32* __restrict__ deg, const uint32* __restrict__ partials,
        uint32* __restrict__ off, uint32* __restrict__ cursor) {
    __shared__ uint32 pair[256];
    const int t = threadIdx.x;
    const int i0 = blockIdx.x * SCAN_CHUNK + 2 * t;
    const int i1 = i0 + 1;
    uint32 e0 = (i0 < N_NODES) ? deg[i0] : 0u;
    uint32 e1 = (i1 < N_NODES) ? deg[i1] : 0u;
    pair[t] = e0 + e1;
    __syncthreads();
    for (int d = 1; d < 256; d <<= 1) {
        uint32 add = (t >= d) ? pair[t - d] : 0u;
        __syncthreads();
        pair[t] += add;
        __syncthreads();
    }
    uint32 base = partials[blockIdx.x] + ((t > 0) ? pair[t - 1] : 0u);
    if (i0 < N_NODES) { off[i0] = base;      cursor[i0] = base; }
    if (i1 < N_NODES) { off[i1] = base + e0; cursor[i1] = base + e0; }
}

// ---------------------------------------------------------------------------
// Bucket-fill sorted source indices
// ---------------------------------------------------------------------------
__global__ __launch_bounds__(256) void k_fill(
        const int* __restrict__ edges, uint32* __restrict__ cursor,
        uint32* __restrict__ sorted_src) {
    int e = blockIdx.x * blockDim.x + threadIdx.x;
    if (e >= N_EDGES) return;
    int src = edges[e];
    int tgt = edges[N_EDGES + e];
    uint32 p = atomicAdd(&cursor[tgt], 1u);
    sorted_src[p] = (uint32)src;
}

// ---------------------------------------------------------------------------
// Fused weight prep: Wc[j][k] bf16 (k<128: W_line, else W_self), biasc = bl+bs
// ---------------------------------------------------------------------------
__global__ __launch_bounds__(256) void k_prep_w(
        const float* __restrict__ Wl, const float* __restrict__ Ws,
        const float* __restrict__ bl, const float* __restrict__ bs,
        unsigned short* __restrict__ Wc, float* __restrict__ biasc) {
    int t = blockIdx.x * 256 + threadIdx.x;
    if (t < D * 256) {
        int j = t >> 8, k = t & 255;
        float v = (k < D) ? Wl[(size_t)j * D + k] : Ws[(size_t)j * D + (k - D)];
        Wc[t] = (unsigned short)f2bf(v);
    }
    if (t < D) biasc[t] = bl[t] + bs[t];
}

// ---------------------------------------------------------------------------
// Gather-mean, half-wave-per-edge: lanes 0-31 process even edges, lanes 32-63
// odd edges. Each lane reads 8 B (4 bf16 cols); one load instruction = 2 rows.
// Unrolled to 4 independent row-loads in flight. Cross-half shfl reduce.
// ---------------------------------------------------------------------------
__global__ __launch_bounds__(256) void k_gather(
        const unsigned short* __restrict__ AbufC,
        unsigned short* __restrict__ Abuf,
        const uint32* __restrict__ off, const uint32* __restrict__ deg,
        const uint32* __restrict__ sorted_src) {
    const int wave = threadIdx.x >> 6;
    const int lane = threadIdx.x & 63;
    const int half = lane >> 5;            // which edge of the pair
    const int cl   = lane & 31;            // column lane: 4 bf16 cols
    const int node = blockIdx.x * 4 + wave;
    if (node >= N_NODES) return;
    const uint32 d = deg[node];
    const uint32 o = off[node];
    const uint32* __restrict__ src = sorted_src + o;

    float a0 = 0.f, a1 = 0.f, a2 = 0.f, a3 = 0.f;     // bank A
    float b0 = 0.f, b1 = 0.f, b2 = 0.f, b3 = 0.f;     // bank B
    uint32 j = 0;
    // 8 edges per iteration: 4 independent 512 B wave-loads in flight
    for (; j + 8 <= d; j += 8) {
        uint32 sA = src[j + 0 + half];
        uint32 sB = src[j + 2 + half];
        uint32 sC = src[j + 4 + half];
        uint32 sD = src[j + 6 + half];
        uint2 uA = *reinterpret_cast<const uint2*>(AbufC + (size_t)sA * 256 + D + cl * 4);
        uint2 uB = *reinterpret_cast<const uint2*>(AbufC + (size_t)sB * 256 + D + cl * 4);
        uint2 uC = *reinterpret_cast<const uint2*>(AbufC + (size_t)sC * 256 + D + cl * 4);
        uint2 uD = *reinterpret_cast<const uint2*>(AbufC + (size_t)sD * 256 + D + cl * 4);
        a0 += bflo(uA.x) + bflo(uB.x);  a1 += bfhi(uA.x) + bfhi(uB.x);
        a2 += bflo(uA.y) + bflo(uB.y);  a3 += bfhi(uA.y) + bfhi(uB.y);
        b0 += bflo(uC.x) + bflo(uD.x);  b1 += bfhi(uC.x) + bfhi(uD.x);
        b2 += bflo(uC.y) + bflo(uD.y);  b3 += bfhi(uC.y) + bfhi(uD.y);
    }
    // 4 edges
    if (j + 4 <= d) {
        uint32 sA = src[j + 0 + half];
        uint32 sB = src[j + 2 + half];
        uint2 uA = *reinterpret_cast<const uint2*>(AbufC + (size_t)sA * 256 + D + cl * 4);
        uint2 uB = *reinterpret_cast<const uint2*>(AbufC + (size_t)sB * 256 + D + cl * 4);
        a0 += bflo(uA.x) + bflo(uB.x);  a1 += bfhi(uA.x) + bfhi(uB.x);
        a2 += bflo(uA.y) + bflo(uB.y);  a3 += bfhi(uA.y) + bfhi(uB.y);
        j += 4;
    }
    // 2 edges
    if (j + 2 <= d) {
        uint32 sA = src[j + half];
        uint2 uA = *reinterpret_cast<const uint2*>(AbufC + (size_t)sA * 256 + D + cl * 4);
        a0 += bflo(uA.x);  a1 += bfhi(uA.x);
        a2 += bflo(uA.y);  a3 += bfhi(uA.y);
        j += 2;
    }
    // last odd edge: half 0 only
    if (j < d && half == 0) {
        uint32 s = src[j];
        uint2 u = *reinterpret_cast<const uint2*>(AbufC + (size_t)s * 256 + D + cl * 4);
        a0 += bflo(u.x);  a1 += bfhi(u.x);
        a2 += bflo(u.y);  a3 += bfhi(u.y);
    }
    a0 += b0; a1 += b1; a2 += b2; a3 += b3;
    // cross-half reduce
    a0 += __shfl(a0, lane ^ 32);
    a1 += __shfl(a1, lane ^ 32);
    a2 += __shfl(a2, lane ^ 32);
    a3 += __shfl(a3, lane ^ 32);
    if (half == 0) {
        const float inv = 1.0f / (float)(d > 0u ? d : 1u);
        uint2 w;
        w.x = f2bf(a0 * inv) | (f2bf(a1 * inv) << 16);
        w.y = f2bf(a2 * inv) | (f2bf(a3 * inv) << 16);
        *reinterpret_cast<uint2*>(Abuf + (size_t)node * 256 + cl * 4) = w;
    }
}

// ---------------------------------------------------------------------------
// MFMA GEMM: out[i][j] = sum_k Abuf[i][k] * Wc[j][k] + biasc[j]
// 4 waves/block; wave = 32 rows x 128 cols = 2x8 fragments of 16x16, K=256.
// No LDS, no barriers: B (64 KB) is L2-resident.
// ---------------------------------------------------------------------------
__global__ __launch_bounds__(256) void sage_mfma(
        const unsigned short* __restrict__ Abuf,
        const unsigned short* __restrict__ Wc,
        const float* __restrict__ biasc,
        float* __restrict__ out) {
    const int tid = threadIdx.x;
    const int wave = tid >> 6;
    const int lane = tid & 63;
    const int lr = lane & 15;              // fragment row/col
    const int lk = (lane >> 4) * 8;        // fragment k-offset
    const long long row0 = (long long)blockIdx.x * 128 + wave * 32;

    f32x4 acc[2][8];
#pragma unroll
    for (int m = 0; m < 2; ++m)
#pragma unroll
        for (int n = 0; n < 8; ++n) acc[m][n] = (f32x4){0.f, 0.f, 0.f, 0.f};

    const unsigned short* pa0 = Abuf + (row0 + lr) * 256 + lk;
    const unsigned short* pa1 = Abuf + (row0 + 16 + lr) * 256 + lk;
    const unsigned short* pb  = Wc + (size_t)lr * 256 + lk;

#pragma unroll
    for (int ks = 0; ks < 8; ++ks) {
        const int k = ks * 32;
        short8 a0 = *reinterpret_cast<const short8*>(pa0 + k);
        short8 a1 = *reinterpret_cast<const short8*>(pa1 + k);
#pragma unroll
        for (int n = 0; n < 8; ++n) {
            short8 b = *reinterpret_cast<const short8*>(pb + (size_t)n * 16 * 256 + k);
            acc[0][n] = __builtin_amdgcn_mfma_f32_16x16x32_bf16(a0, b, acc[0][n], 0, 0, 0);
            acc[1][n] = __builtin_amdgcn_mfma_f32_16x16x32_bf16(a1, b, acc[1][n], 0, 0, 0);
        }
    }

    // epilogue: bias + store (C/D: col = lane&15, row = (lane>>4)*4 + reg)
    float bv[8];
#pragma unroll
    for (int n = 0; n < 8; ++n) bv[n] = biasc[n * 16 + lr];

    const int rq = (lane >> 4) * 4;
#pragma unroll
    for (int m = 0; m < 2; ++m) {
#pragma unroll
        for (int r = 0; r < 4; ++r) {
            const long long row = row0 + m * 16 + rq + r;
            if (row < N_NODES) {
                float* orow = out + row * D;
#pragma unroll
                for (int n = 0; n < 8; ++n)
                    orow[n * 16 + lr] = acc[m][n][r] + bv[n];
            }
        }
    }
}

extern "C" void kernel_launch(void* const* d_in, const int* in_sizes, int n_in,
                              void* d_out, int out_size, void* d_ws, size_t ws_size,
                              hipStream_t stream) {
    const float* nf    = (const float*)d_in[0];
    const int*   edges = (const int*)d_in[1];
    const float* Wl    = (const float*)d_in[2];
    const float* bl    = (const float*)d_in[3];
    const float* Ws    = (const float*)d_in[4];
    const float* bs    = (const float*)d_in[5];
    float* out = (float*)d_out;

    // workspace layout
    char* p = (char*)d_ws;
    unsigned short* Abuf = (unsigned short*)p; p += (size_t)M_PAD * 256 * sizeof(unsigned short);
    uint32* deg        = (uint32*)p; p += (size_t)N_NODES * sizeof(uint32);
    uint32* off        = (uint32*)p; p += (size_t)N_NODES * sizeof(uint32);
    uint32* cursor     = (uint32*)p; p += (size_t)N_NODES * sizeof(uint32);
    uint32* sorted_src = (uint32*)p; p += (size_t)N_EDGES * sizeof(uint32);
    uint32* partials   = (uint32*)p; p += 1024;
    // Wc/biasc overlap the (dead-after-k_fill) cursor buffer
    unsigned short* Wc = (unsigned short*)cursor;              // 64 KB
    float* biasc       = (float*)(cursor + (D * 256) / 2);     // 512 B

    hipMemsetAsync(deg, 0, (size_t)N_NODES * sizeof(uint32), stream);

    k_convert<<<(N_NODES * 16 + 255) / 256, 256, 0, stream>>>(nf, Abuf);
    k_hist<<<(N_EDGES + 255) / 256, 256, 0, stream>>>(edges, deg);
    k_scan1<<<SCAN_NBLK, 256, 0, stream>>>(deg, partials);
    k_scan2<<<1, 256, 0, stream>>>(partials);
    k_scan3<<<SCAN_NBLK, 256, 0, stream>>>(deg, partials, off, cursor);
    k_fill<<<(N_EDGES + 255) / 256, 256, 0, stream>>>(edges, cursor, sorted_src);
    k_prep_w<<<(D * 256 + 255) / 256, 256, 0, stream>>>(Wl, Ws, bl, bs, Wc, biasc);
    k_gather<<<(N_NODES + 3) / 4, 256, 0, stream>>>(Abuf, Abuf, off, deg, sorted_src);
    sage_mfma<<<M_PAD / 128, 256, 0, stream>>>(Abuf, Wc, biasc, out);
}

// Round 5
// 147.443 us; speedup vs baseline: 7.8035x; 1.1492x over previous
//
#include <hip/hip_runtime.h>

#define N_NODES 100000
#define N_EDGES 600000
#define D 128
#define M_PAD 100096            // 782 * 128

#define SCAN_CHUNK 512
#define SCAN_NBLK ((N_NODES + SCAN_CHUNK - 1) / SCAN_CHUNK)   // 196

typedef unsigned int uint32;
typedef __attribute__((ext_vector_type(8))) short short8;
typedef __attribute__((ext_vector_type(4))) float f32x4;

__device__ __forceinline__ uint32 f2bf(float x) {          // RNE f32 -> bf16
    uint32 u = __float_as_uint(x);
    return (u + 0x7FFFu + ((u >> 16) & 1u)) >> 16;
}
__device__ __forceinline__ float bflo(uint32 u) { return __uint_as_float(u << 16); }
__device__ __forceinline__ float bfhi(uint32 u) { return __uint_as_float(u & 0xFFFF0000u); }

// ---------------------------------------------------------------------------
// Convert nf -> bf16 upper K-half of Abuf rows; fused degree histogram.
// ---------------------------------------------------------------------------
__global__ __launch_bounds__(256) void k_convert_hist(
        const float* __restrict__ nf, unsigned short* __restrict__ Abuf,
        const int* __restrict__ edges, uint32* __restrict__ deg) {
    int idx = blockIdx.x * 256 + threadIdx.x;          // 0 .. 1.6M
    if (idx < N_NODES * 16) {
        int r = idx >> 4;
        int c = (idx & 15) * 8;
        const float4 v0 = *reinterpret_cast<const float4*>(nf + (size_t)r * D + c);
        const float4 v1 = *reinterpret_cast<const float4*>(nf + (size_t)r * D + c + 4);
        uint4 w;
        w.x = f2bf(v0.x) | (f2bf(v0.y) << 16);
        w.y = f2bf(v0.z) | (f2bf(v0.w) << 16);
        w.z = f2bf(v1.x) | (f2bf(v1.y) << 16);
        w.w = f2bf(v1.z) | (f2bf(v1.w) << 16);
        *reinterpret_cast<uint4*>(Abuf + (size_t)r * 256 + D + c) = w;
    }
    if (idx < N_EDGES) {
        atomicAdd(&deg[edges[N_EDGES + idx]], 1u);
    }
}

// ---------------------------------------------------------------------------
// Scan phase 1: per-chunk sums
// ---------------------------------------------------------------------------
__global__ __launch_bounds__(256) void k_scan1(
        const uint32* __restrict__ deg, uint32* __restrict__ partials) {
    __shared__ uint32 s[256];
    const int t = threadIdx.x;
    const int base = blockIdx.x * SCAN_CHUNK;
    uint32 v = 0;
    int i0 = base + t, i1 = base + 256 + t;
    if (i0 < N_NODES) v += deg[i0];
    if (i1 < N_NODES) v += deg[i1];
    s[t] = v;
    __syncthreads();
    for (int d = 128; d > 0; d >>= 1) {
        if (t < d) s[t] += s[t + d];
        __syncthreads();
    }
    if (t == 0) partials[blockIdx.x] = s[0];
}

// ---------------------------------------------------------------------------
// Scan phase 2: exclusive scan of partials (single block)
// ---------------------------------------------------------------------------
__global__ __launch_bounds__(256) void k_scan2(uint32* __restrict__ partials) {
    __shared__ uint32 s[256];
    const int t = threadIdx.x;
    s[t] = (t < SCAN_NBLK) ? partials[t] : 0u;
    __syncthreads();
    for (int d = 1; d < 256; d <<= 1) {
        uint32 add = (t >= d) ? s[t - d] : 0u;
        __syncthreads();
        s[t] += add;
        __syncthreads();
    }
    if (t < SCAN_NBLK) partials[t] = (t > 0) ? s[t - 1] : 0u;
}

// ---------------------------------------------------------------------------
// Scan phase 3: per-chunk exclusive scan + base -> off, cursor
// ---------------------------------------------------------------------------
__global__ __launch_bounds__(256) void k_scan3(
        const uint32* __restrict__ deg, const uint32* __restrict__ partials,
        uint32* __restrict__ off, uint32* __restrict__ cursor) {
    __shared__ uint32 pair[256];
    const int t = threadIdx.x;
    const int i0 = blockIdx.x * SCAN_CHUNK + 2 * t;
    const int i1 = i0 + 1;
    uint32 e0 = (i0 < N_NODES) ? deg[i0] : 0u;
    uint32 e1 = (i1 < N_NODES) ? deg[i1] : 0u;
    pair[t] = e0 + e1;
    __syncthreads();
    for (int d = 1; d < 256; d <<= 1) {
        uint32 add = (t >= d) ? pair[t - d] : 0u;
        __syncthreads();
        pair[t] += add;
        __syncthreads();
    }
    uint32 base = partials[blockIdx.x] + ((t > 0) ? pair[t - 1] : 0u);
    if (i0 < N_NODES) { off[i0] = base;      cursor[i0] = base; }
    if (i1 < N_NODES) { off[i1] = base + e0; cursor[i1] = base + e0; }
}

// ---------------------------------------------------------------------------
// Bucket-fill sorted src; fused W-prep into MFMA-fragment order + bias.
// WcF chunk c (16B): lane=c&63, f2=c>>6; ks=f2&7, nn=(f2>>3)&3, ch=f2>>5;
//   j = ch*64 + nn*16 + (lane&15); kb = ks*32 + (lane>>4)*8
// ---------------------------------------------------------------------------
__global__ __launch_bounds__(256) void k_fill_prep(
        const int* __restrict__ edges, uint32* __restrict__ cursor,
        uint32* __restrict__ sorted_src,
        const float* __restrict__ Wl, const float* __restrict__ Ws,
        const float* __restrict__ bl, const float* __restrict__ bs,
        unsigned short* __restrict__ WcF, float* __restrict__ biasc) {
    int idx = blockIdx.x * 256 + threadIdx.x;
    if (idx < N_EDGES) {
        int src = edges[idx];
        int tgt = edges[N_EDGES + idx];
        uint32 p = atomicAdd(&cursor[tgt], 1u);
        sorted_src[p] = (uint32)src;
    }
    if (idx < 4096) {
        int lane = idx & 63, f2 = idx >> 6;
        int ks = f2 & 7, nn = (f2 >> 3) & 3, ch = f2 >> 5;
        int j = ch * 64 + nn * 16 + (lane & 15);
        int kb = ks * 32 + (lane >> 4) * 8;
        const float* srcp = (kb < D) ? (Wl + (size_t)j * D + kb)
                                     : (Ws + (size_t)j * D + (kb - D));
        const float4 v0 = *reinterpret_cast<const float4*>(srcp);
        const float4 v1 = *reinterpret_cast<const float4*>(srcp + 4);
        uint4 w;
        w.x = f2bf(v0.x) | (f2bf(v0.y) << 16);
        w.y = f2bf(v0.z) | (f2bf(v0.w) << 16);
        w.z = f2bf(v1.x) | (f2bf(v1.y) << 16);
        w.w = f2bf(v1.z) | (f2bf(v1.w) << 16);
        *reinterpret_cast<uint4*>(WcF + (size_t)idx * 8) = w;
    }
    if (idx < D) biasc[idx] = bl[idx] + bs[idx];
}

// ---------------------------------------------------------------------------
// Gather-mean, half-wave-per-edge (lanes 0-31 even edge, 32-63 odd edge),
// 8-edge unroll = 4 independent 512 B row-loads in flight.
// ---------------------------------------------------------------------------
__global__ __launch_bounds__(256) void k_gather(
        const unsigned short* __restrict__ AbufC,
        unsigned short* __restrict__ Abuf,
        const uint32* __restrict__ off, const uint32* __restrict__ deg,
        const uint32* __restrict__ sorted_src) {
    const int wave = threadIdx.x >> 6;
    const int lane = threadIdx.x & 63;
    const int half = lane >> 5;
    const int cl   = lane & 31;
    const int node = blockIdx.x * 4 + wave;
    if (node >= N_NODES) return;
    const uint32 d = deg[node];
    const uint32 o = off[node];
    const uint32* __restrict__ src = sorted_src + o;

    float a0 = 0.f, a1 = 0.f, a2 = 0.f, a3 = 0.f;
    float b0 = 0.f, b1 = 0.f, b2 = 0.f, b3 = 0.f;
    uint32 j = 0;
    for (; j + 8 <= d; j += 8) {
        uint32 sA = src[j + 0 + half];
        uint32 sB = src[j + 2 + half];
        uint32 sC = src[j + 4 + half];
        uint32 sD = src[j + 6 + half];
        uint2 uA = *reinterpret_cast<const uint2*>(AbufC + (size_t)sA * 256 + D + cl * 4);
        uint2 uB = *reinterpret_cast<const uint2*>(AbufC + (size_t)sB * 256 + D + cl * 4);
        uint2 uC = *reinterpret_cast<const uint2*>(AbufC + (size_t)sC * 256 + D + cl * 4);
        uint2 uD = *reinterpret_cast<const uint2*>(AbufC + (size_t)sD * 256 + D + cl * 4);
        a0 += bflo(uA.x) + bflo(uB.x);  a1 += bfhi(uA.x) + bfhi(uB.x);
        a2 += bflo(uA.y) + bflo(uB.y);  a3 += bfhi(uA.y) + bfhi(uB.y);
        b0 += bflo(uC.x) + bflo(uD.x);  b1 += bfhi(uC.x) + bfhi(uD.x);
        b2 += bflo(uC.y) + bflo(uD.y);  b3 += bfhi(uC.y) + bfhi(uD.y);
    }
    if (j + 4 <= d) {
        uint32 sA = src[j + 0 + half];
        uint32 sB = src[j + 2 + half];
        uint2 uA = *reinterpret_cast<const uint2*>(AbufC + (size_t)sA * 256 + D + cl * 4);
        uint2 uB = *reinterpret_cast<const uint2*>(AbufC + (size_t)sB * 256 + D + cl * 4);
        a0 += bflo(uA.x) + bflo(uB.x);  a1 += bfhi(uA.x) + bfhi(uB.x);
        a2 += bflo(uA.y) + bflo(uB.y);  a3 += bfhi(uA.y) + bfhi(uB.y);
        j += 4;
    }
    if (j + 2 <= d) {
        uint32 sA = src[j + half];
        uint2 uA = *reinterpret_cast<const uint2*>(AbufC + (size_t)sA * 256 + D + cl * 4);
        a0 += bflo(uA.x);  a1 += bfhi(uA.x);
        a2 += bflo(uA.y);  a3 += bfhi(uA.y);
        j += 2;
    }
    if (j < d && half == 0) {
        uint32 s = src[j];
        uint2 u = *reinterpret_cast<const uint2*>(AbufC + (size_t)s * 256 + D + cl * 4);
        a0 += bflo(u.x);  a1 += bfhi(u.x);
        a2 += bflo(u.y);  a3 += bfhi(u.y);
    }
    a0 += b0; a1 += b1; a2 += b2; a3 += b3;
    a0 += __shfl(a0, lane ^ 32);
    a1 += __shfl(a1, lane ^ 32);
    a2 += __shfl(a2, lane ^ 32);
    a3 += __shfl(a3, lane ^ 32);
    if (half == 0) {
        const float inv = 1.0f / (float)(d > 0u ? d : 1u);
        uint2 w;
        w.x = f2bf(a0 * inv) | (f2bf(a1 * inv) << 16);
        w.y = f2bf(a2 * inv) | (f2bf(a3 * inv) << 16);
        *reinterpret_cast<uint2*>(Abuf + (size_t)node * 256 + cl * 4) = w;
    }
}

// ---------------------------------------------------------------------------
// MFMA GEMM: block = 64 rows x 64 cols (colhalf ch = blockIdx&1), 4 waves of
// 16 rows each. B pre-fragmented in LDS (32 KB): ds_read_b128 at base+lane*16
// -> conflict-free. A streamed from global; row pair-blocks share A via L3.
// ---------------------------------------------------------------------------
__global__ __launch_bounds__(256) void sage_mfma(
        const unsigned short* __restrict__ Abuf,
        const unsigned short* __restrict__ WcF,
        const float* __restrict__ biasc,
        float* __restrict__ out) {
    __shared__ unsigned short WcL[16384];       // 32 KB = 32 frags x 1 KB
    const int tid = threadIdx.x;
    const int rb = blockIdx.x >> 1;
    const int ch = blockIdx.x & 1;

    // stage this col-half's fragments linearly (2048 x 16B chunks)
    const unsigned short* wsrc = WcF + (size_t)ch * 16384;
#pragma unroll
    for (int i = 0; i < 8; ++i) {
        const int o = (i * 256 + tid) * 8;
        *reinterpret_cast<short8*>(&WcL[o]) = *reinterpret_cast<const short8*>(wsrc + o);
    }
    __syncthreads();

    const int wave = tid >> 6;
    const int lane = tid & 63;
    const int lr = lane & 15;
    const int lk = (lane >> 4) * 8;
    const long long row0 = (long long)rb * 64 + wave * 16;

    f32x4 acc[4];
#pragma unroll
    for (int n = 0; n < 4; ++n) acc[n] = (f32x4){0.f, 0.f, 0.f, 0.f};

    const unsigned short* pa = Abuf + (row0 + lr) * 256 + lk;
#pragma unroll
    for (int ks = 0; ks < 8; ++ks) {
        short8 a = *reinterpret_cast<const short8*>(pa + ks * 32);
#pragma unroll
        for (int n = 0; n < 4; ++n) {
            short8 b = *reinterpret_cast<const short8*>(&WcL[((n * 8 + ks) * 64 + lane) * 8]);
            acc[n] = __builtin_amdgcn_mfma_f32_16x16x32_bf16(a, b, acc[n], 0, 0, 0);
        }
    }

    // epilogue (C/D: col = lane&15, row = (lane>>4)*4 + reg)
    float bv[4];
#pragma unroll
    for (int n = 0; n < 4; ++n) bv[n] = biasc[ch * 64 + n * 16 + lr];

    const int rq = (lane >> 4) * 4;
#pragma unroll
    for (int r = 0; r < 4; ++r) {
        const long long row = row0 + rq + r;
        if (row < N_NODES) {
            float* orow = out + row * D + ch * 64;
#pragma unroll
            for (int n = 0; n < 4; ++n)
                orow[n * 16 + lr] = acc[n][r] + bv[n];
        }
    }
}

extern "C" void kernel_launch(void* const* d_in, const int* in_sizes, int n_in,
                              void* d_out, int out_size, void* d_ws, size_t ws_size,
                              hipStream_t stream) {
    const float* nf    = (const float*)d_in[0];
    const int*   edges = (const int*)d_in[1];
    const float* Wl    = (const float*)d_in[2];
    const float* bl    = (const float*)d_in[3];
    const float* Ws    = (const float*)d_in[4];
    const float* bs    = (const float*)d_in[5];
    float* out = (float*)d_out;

    // workspace layout
    char* p = (char*)d_ws;
    unsigned short* Abuf = (unsigned short*)p; p += (size_t)M_PAD * 256 * sizeof(unsigned short);
    uint32* deg        = (uint32*)p; p += (size_t)N_NODES * sizeof(uint32);
    uint32* off        = (uint32*)p; p += (size_t)N_NODES * sizeof(uint32);
    uint32* cursor     = (uint32*)p; p += (size_t)N_NODES * sizeof(uint32);
    uint32* sorted_src = (uint32*)p; p += (size_t)N_EDGES * sizeof(uint32);
    uint32* partials   = (uint32*)p; p += 1024;
    unsigned short* WcF = (unsigned short*)p; p += (size_t)D * 256 * sizeof(unsigned short);
    float* biasc       = (float*)p;

    hipMemsetAsync(deg, 0, (size_t)N_NODES * sizeof(uint32), stream);

    k_convert_hist<<<(N_NODES * 16 + 255) / 256, 256, 0, stream>>>(nf, Abuf, edges, deg);
    k_scan1<<<SCAN_NBLK, 256, 0, stream>>>(deg, partials);
    k_scan2<<<1, 256, 0, stream>>>(partials);
    k_scan3<<<SCAN_NBLK, 256, 0, stream>>>(deg, partials, off, cursor);
    k_fill_prep<<<(N_EDGES + 255) / 256, 256, 0, stream>>>(edges, cursor, sorted_src,
                                                           Wl, Ws, bl, bs, WcF, biasc);
    k_gather<<<(N_NODES + 3) / 4, 256, 0, stream>>>(Abuf, Abuf, off, deg, sorted_src);
    sage_mfma<<<(M_PAD / 64) * 2, 256, 0, stream>>>(Abuf, WcF, biasc, out);
}

// Round 6
// 145.993 us; speedup vs baseline: 7.8810x; 1.0099x over previous
//
#include <hip/hip_runtime.h>

#define N_NODES 100000
#define N_EDGES 600000
#define D 128
#define M_PAD 100096            // 782 * 128

#define SCAN_CHUNK 512
#define SCAN_NBLK ((N_NODES + SCAN_CHUNK - 1) / SCAN_CHUNK)   // 196

typedef unsigned int uint32;
typedef __attribute__((ext_vector_type(8))) short short8;
typedef __attribute__((ext_vector_type(4))) float f32x4;

__device__ __forceinline__ uint32 f2bf(float x) {          // RNE f32 -> bf16
    uint32 u = __float_as_uint(x);
    return (u + 0x7FFFu + ((u >> 16) & 1u)) >> 16;
}
__device__ __forceinline__ float bflo(uint32 u) { return __uint_as_float(u << 16); }
__device__ __forceinline__ float bfhi(uint32 u) { return __uint_as_float(u & 0xFFFF0000u); }

// ---------------------------------------------------------------------------
// Zero the degree histogram (replaces 40 us rocclr fillBuffer with ~2 us).
// ---------------------------------------------------------------------------
__global__ __launch_bounds__(256) void k_zero(uint32* __restrict__ deg) {
    int i = blockIdx.x * 256 + threadIdx.x;
    if (i < N_NODES) deg[i] = 0u;
}

// ---------------------------------------------------------------------------
// Convert nf -> bf16 upper K-half of Abuf rows; fused degree histogram.
// ---------------------------------------------------------------------------
__global__ __launch_bounds__(256) void k_convert_hist(
        const float* __restrict__ nf, unsigned short* __restrict__ Abuf,
        const int* __restrict__ edges, uint32* __restrict__ deg) {
    int idx = blockIdx.x * 256 + threadIdx.x;          // 0 .. 1.6M
    if (idx < N_NODES * 16) {
        int r = idx >> 4;
        int c = (idx & 15) * 8;
        const float4 v0 = *reinterpret_cast<const float4*>(nf + (size_t)r * D + c);
        const float4 v1 = *reinterpret_cast<const float4*>(nf + (size_t)r * D + c + 4);
        uint4 w;
        w.x = f2bf(v0.x) | (f2bf(v0.y) << 16);
        w.y = f2bf(v0.z) | (f2bf(v0.w) << 16);
        w.z = f2bf(v1.x) | (f2bf(v1.y) << 16);
        w.w = f2bf(v1.z) | (f2bf(v1.w) << 16);
        *reinterpret_cast<uint4*>(Abuf + (size_t)r * 256 + D + c) = w;
    }
    if (idx < N_EDGES) {
        atomicAdd(&deg[edges[N_EDGES + idx]], 1u);
    }
}

// ---------------------------------------------------------------------------
// Scan phase 1: per-chunk sums
// ---------------------------------------------------------------------------
__global__ __launch_bounds__(256) void k_scan1(
        const uint32* __restrict__ deg, uint32* __restrict__ partials) {
    __shared__ uint32 s[256];
    const int t = threadIdx.x;
    const int base = blockIdx.x * SCAN_CHUNK;
    uint32 v = 0;
    int i0 = base + t, i1 = base + 256 + t;
    if (i0 < N_NODES) v += deg[i0];
    if (i1 < N_NODES) v += deg[i1];
    s[t] = v;
    __syncthreads();
    for (int d = 128; d > 0; d >>= 1) {
        if (t < d) s[t] += s[t + d];
        __syncthreads();
    }
    if (t == 0) partials[blockIdx.x] = s[0];
}

// ---------------------------------------------------------------------------
// Scan phase 2+3 merged: each block reduces partials[0..blockIdx) itself,
// then does its chunk-local exclusive scan -> off, cursor.
// ---------------------------------------------------------------------------
__global__ __launch_bounds__(256) void k_scan3(
        const uint32* __restrict__ deg, const uint32* __restrict__ partials,
        uint32* __restrict__ off, uint32* __restrict__ cursor) {
    __shared__ uint32 red[256];
    __shared__ uint32 pair[256];
    const int t = threadIdx.x;
    // block base = sum of partials[0..blockIdx.x)
    red[t] = (t < blockIdx.x) ? partials[t] : 0u;     // SCAN_NBLK=196 < 256
    __syncthreads();
    for (int d2 = 128; d2 > 0; d2 >>= 1) {
        if (t < d2) red[t] += red[t + d2];
        __syncthreads();
    }
    const uint32 blockbase = red[0];

    const int i0 = blockIdx.x * SCAN_CHUNK + 2 * t;
    const int i1 = i0 + 1;
    uint32 e0 = (i0 < N_NODES) ? deg[i0] : 0u;
    uint32 e1 = (i1 < N_NODES) ? deg[i1] : 0u;
    pair[t] = e0 + e1;
    __syncthreads();
    for (int d = 1; d < 256; d <<= 1) {
        uint32 add = (t >= d) ? pair[t - d] : 0u;
        __syncthreads();
        pair[t] += add;
        __syncthreads();
    }
    uint32 base = blockbase + ((t > 0) ? pair[t - 1] : 0u);
    if (i0 < N_NODES) { off[i0] = base;      cursor[i0] = base; }
    if (i1 < N_NODES) { off[i1] = base + e0; cursor[i1] = base + e0; }
}

// ---------------------------------------------------------------------------
// Bucket-fill sorted src; fused W-prep into MFMA-fragment order + bias.
// WcF chunk c (16B): lane=c&63, f2=c>>6; ks=f2&7, nn=(f2>>3)&3, ch=f2>>5;
//   j = ch*64 + nn*16 + (lane&15); kb = ks*32 + (lane>>4)*8
// ---------------------------------------------------------------------------
__global__ __launch_bounds__(256) void k_fill_prep(
        const int* __restrict__ edges, uint32* __restrict__ cursor,
        uint32* __restrict__ sorted_src,
        const float* __restrict__ Wl, const float* __restrict__ Ws,
        const float* __restrict__ bl, const float* __restrict__ bs,
        unsigned short* __restrict__ WcF, float* __restrict__ biasc) {
    int idx = blockIdx.x * 256 + threadIdx.x;
    if (idx < N_EDGES) {
        int src = edges[idx];
        int tgt = edges[N_EDGES + idx];
        uint32 p = atomicAdd(&cursor[tgt], 1u);
        sorted_src[p] = (uint32)src;
    }
    if (idx < 4096) {
        int lane = idx & 63, f2 = idx >> 6;
        int ks = f2 & 7, nn = (f2 >> 3) & 3, ch = f2 >> 5;
        int j = ch * 64 + nn * 16 + (lane & 15);
        int kb = ks * 32 + (lane >> 4) * 8;
        const float* srcp = (kb < D) ? (Wl + (size_t)j * D + kb)
                                     : (Ws + (size_t)j * D + (kb - D));
        const float4 v0 = *reinterpret_cast<const float4*>(srcp);
        const float4 v1 = *reinterpret_cast<const float4*>(srcp + 4);
        uint4 w;
        w.x = f2bf(v0.x) | (f2bf(v0.y) << 16);
        w.y = f2bf(v0.z) | (f2bf(v0.w) << 16);
        w.z = f2bf(v1.x) | (f2bf(v1.y) << 16);
        w.w = f2bf(v1.z) | (f2bf(v1.w) << 16);
        *reinterpret_cast<uint4*>(WcF + (size_t)idx * 8) = w;
    }
    if (idx < D) biasc[idx] = bl[idx] + bs[idx];
}

// ---------------------------------------------------------------------------
// Gather-mean, half-wave-per-edge (lanes 0-31 even edge, 32-63 odd edge),
// 8-edge unroll = 4 independent 512 B row-loads in flight.
// ---------------------------------------------------------------------------
__global__ __launch_bounds__(256) void k_gather(
        const unsigned short* __restrict__ AbufC,
        unsigned short* __restrict__ Abuf,
        const uint32* __restrict__ off, const uint32* __restrict__ deg,
        const uint32* __restrict__ sorted_src) {
    const int wave = threadIdx.x >> 6;
    const int lane = threadIdx.x & 63;
    const int half = lane >> 5;
    const int cl   = lane & 31;
    const int node = blockIdx.x * 4 + wave;
    if (node >= N_NODES) return;
    const uint32 d = deg[node];
    const uint32 o = off[node];
    const uint32* __restrict__ src = sorted_src + o;

    float a0 = 0.f, a1 = 0.f, a2 = 0.f, a3 = 0.f;
    float b0 = 0.f, b1 = 0.f, b2 = 0.f, b3 = 0.f;
    uint32 j = 0;
    for (; j + 8 <= d; j += 8) {
        uint32 sA = src[j + 0 + half];
        uint32 sB = src[j + 2 + half];
        uint32 sC = src[j + 4 + half];
        uint32 sD = src[j + 6 + half];
        uint2 uA = *reinterpret_cast<const uint2*>(AbufC + (size_t)sA * 256 + D + cl * 4);
        uint2 uB = *reinterpret_cast<const uint2*>(AbufC + (size_t)sB * 256 + D + cl * 4);
        uint2 uC = *reinterpret_cast<const uint2*>(AbufC + (size_t)sC * 256 + D + cl * 4);
        uint2 uD = *reinterpret_cast<const uint2*>(AbufC + (size_t)sD * 256 + D + cl * 4);
        a0 += bflo(uA.x) + bflo(uB.x);  a1 += bfhi(uA.x) + bfhi(uB.x);
        a2 += bflo(uA.y) + bflo(uB.y);  a3 += bfhi(uA.y) + bfhi(uB.y);
        b0 += bflo(uC.x) + bflo(uD.x);  b1 += bfhi(uC.x) + bfhi(uD.x);
        b2 += bflo(uC.y) + bflo(uD.y);  b3 += bfhi(uC.y) + bfhi(uD.y);
    }
    if (j + 4 <= d) {
        uint32 sA = src[j + 0 + half];
        uint32 sB = src[j + 2 + half];
        uint2 uA = *reinterpret_cast<const uint2*>(AbufC + (size_t)sA * 256 + D + cl * 4);
        uint2 uB = *reinterpret_cast<const uint2*>(AbufC + (size_t)sB * 256 + D + cl * 4);
        a0 += bflo(uA.x) + bflo(uB.x);  a1 += bfhi(uA.x) + bfhi(uB.x);
        a2 += bflo(uA.y) + bflo(uB.y);  a3 += bfhi(uA.y) + bfhi(uB.y);
        j += 4;
    }
    if (j + 2 <= d) {
        uint32 sA = src[j + half];
        uint2 uA = *reinterpret_cast<const uint2*>(AbufC + (size_t)sA * 256 + D + cl * 4);
        a0 += bflo(uA.x);  a1 += bfhi(uA.x);
        a2 += bflo(uA.y);  a3 += bfhi(uA.y);
        j += 2;
    }
    if (j < d && half == 0) {
        uint32 s = src[j];
        uint2 u = *reinterpret_cast<const uint2*>(AbufC + (size_t)s * 256 + D + cl * 4);
        a0 += bflo(u.x);  a1 += bfhi(u.x);
        a2 += bflo(u.y);  a3 += bfhi(u.y);
    }
    a0 += b0; a1 += b1; a2 += b2; a3 += b3;
    a0 += __shfl(a0, lane ^ 32);
    a1 += __shfl(a1, lane ^ 32);
    a2 += __shfl(a2, lane ^ 32);
    a3 += __shfl(a3, lane ^ 32);
    if (half == 0) {
        const float inv = 1.0f / (float)(d > 0u ? d : 1u);
        uint2 w;
        w.x = f2bf(a0 * inv) | (f2bf(a1 * inv) << 16);
        w.y = f2bf(a2 * inv) | (f2bf(a3 * inv) << 16);
        *reinterpret_cast<uint2*>(Abuf + (size_t)node * 256 + cl * 4) = w;
    }
}

// ---------------------------------------------------------------------------
// MFMA GEMM: block = 64 rows x 64 cols (colhalf ch = blockIdx&1), 4 waves of
// 16 rows each. B pre-fragmented in LDS (32 KB): ds_read_b128 at base+lane*16
// -> conflict-free. A streamed from global; row pair-blocks share A via L3.
// ---------------------------------------------------------------------------
__global__ __launch_bounds__(256) void sage_mfma(
        const unsigned short* __restrict__ Abuf,
        const unsigned short* __restrict__ WcF,
        const float* __restrict__ biasc,
        float* __restrict__ out) {
    __shared__ unsigned short WcL[16384];       // 32 KB = 32 frags x 1 KB
    const int tid = threadIdx.x;
    const int rb = blockIdx.x >> 1;
    const int ch = blockIdx.x & 1;

    // stage this col-half's fragments linearly (2048 x 16B chunks)
    const unsigned short* wsrc = WcF + (size_t)ch * 16384;
#pragma unroll
    for (int i = 0; i < 8; ++i) {
        const int o = (i * 256 + tid) * 8;
        *reinterpret_cast<short8*>(&WcL[o]) = *reinterpret_cast<const short8*>(wsrc + o);
    }
    __syncthreads();

    const int wave = tid >> 6;
    const int lane = tid & 63;
    const int lr = lane & 15;
    const int lk = (lane >> 4) * 8;
    const long long row0 = (long long)rb * 64 + wave * 16;

    f32x4 acc[4];
#pragma unroll
    for (int n = 0; n < 4; ++n) acc[n] = (f32x4){0.f, 0.f, 0.f, 0.f};

    const unsigned short* pa = Abuf + (row0 + lr) * 256 + lk;
#pragma unroll
    for (int ks = 0; ks < 8; ++ks) {
        short8 a = *reinterpret_cast<const short8*>(pa + ks * 32);
#pragma unroll
        for (int n = 0; n < 4; ++n) {
            short8 b = *reinterpret_cast<const short8*>(&WcL[((n * 8 + ks) * 64 + lane) * 8]);
            acc[n] = __builtin_amdgcn_mfma_f32_16x16x32_bf16(a, b, acc[n], 0, 0, 0);
        }
    }

    // epilogue (C/D: col = lane&15, row = (lane>>4)*4 + reg)
    float bv[4];
#pragma unroll
    for (int n = 0; n < 4; ++n) bv[n] = biasc[ch * 64 + n * 16 + lr];

    const int rq = (lane >> 4) * 4;
#pragma unroll
    for (int r = 0; r < 4; ++r) {
        const long long row = row0 + rq + r;
        if (row < N_NODES) {
            float* orow = out + row * D + ch * 64;
#pragma unroll
            for (int n = 0; n < 4; ++n)
                orow[n * 16 + lr] = acc[n][r] + bv[n];
        }
    }
}

extern "C" void kernel_launch(void* const* d_in, const int* in_sizes, int n_in,
                              void* d_out, int out_size, void* d_ws, size_t ws_size,
                              hipStream_t stream) {
    const float* nf    = (const float*)d_in[0];
    const int*   edges = (const int*)d_in[1];
    const float* Wl    = (const float*)d_in[2];
    const float* bl    = (const float*)d_in[3];
    const float* Ws    = (const float*)d_in[4];
    const float* bs    = (const float*)d_in[5];
    float* out = (float*)d_out;

    // workspace layout
    char* p = (char*)d_ws;
    unsigned short* Abuf = (unsigned short*)p; p += (size_t)M_PAD * 256 * sizeof(unsigned short);
    uint32* deg        = (uint32*)p; p += (size_t)N_NODES * sizeof(uint32);
    uint32* off        = (uint32*)p; p += (size_t)N_NODES * sizeof(uint32);
    uint32* cursor     = (uint32*)p; p += (size_t)N_NODES * sizeof(uint32);
    uint32* sorted_src = (uint32*)p; p += (size_t)N_EDGES * sizeof(uint32);
    uint32* partials   = (uint32*)p; p += 1024;
    unsigned short* WcF = (unsigned short*)p; p += (size_t)D * 256 * sizeof(unsigned short);
    float* biasc       = (float*)p;

    k_zero<<<(N_NODES + 255) / 256, 256, 0, stream>>>(deg);
    k_convert_hist<<<(N_NODES * 16 + 255) / 256, 256, 0, stream>>>(nf, Abuf, edges, deg);
    k_scan1<<<SCAN_NBLK, 256, 0, stream>>>(deg, partials);
    k_scan3<<<SCAN_NBLK, 256, 0, stream>>>(deg, partials, off, cursor);
    k_fill_prep<<<(N_EDGES + 255) / 256, 256, 0, stream>>>(edges, cursor, sorted_src,
                                                           Wl, Ws, bl, bs, WcF, biasc);
    k_gather<<<(N_NODES + 3) / 4, 256, 0, stream>>>(Abuf, Abuf, off, deg, sorted_src);
    sage_mfma<<<(M_PAD / 64) * 2, 256, 0, stream>>>(Abuf, WcF, biasc, out);
}

// Round 7
// 115.752 us; speedup vs baseline: 9.9401x; 1.2613x over previous
//
#include <hip/hip_runtime.h>

#define N_NODES 100000
#define N_EDGES 600000
#define D 128
#define M_PAD 100096            // 782 * 128

#define SCAN_CHUNK 512
#define SCAN_NBLK ((N_NODES + SCAN_CHUNK - 1) / SCAN_CHUNK)   // 196

typedef unsigned int uint32;
typedef __attribute__((ext_vector_type(8))) short short8;
typedef __attribute__((ext_vector_type(4))) float f32x4;

__device__ __forceinline__ uint32 f2bf(float x) {          // RNE f32 -> bf16
    uint32 u = __float_as_uint(x);
    return (u + 0x7FFFu + ((u >> 16) & 1u)) >> 16;
}
__device__ __forceinline__ float bflo(uint32 u) { return __uint_as_float(u << 16); }
__device__ __forceinline__ float bfhi(uint32 u) { return __uint_as_float(u & 0xFFFF0000u); }

// ---------------------------------------------------------------------------
// Zero the degree histogram.
// ---------------------------------------------------------------------------
__global__ __launch_bounds__(256) void k_zero(uint32* __restrict__ deg) {
    int i = blockIdx.x * 256 + threadIdx.x;
    if (i < N_NODES) deg[i] = 0u;
}

// ---------------------------------------------------------------------------
// Convert nf -> bf16 upper K-half of Abuf rows; fused degree histogram that
// ALSO records each edge's within-bucket rank (atomicAdd return value).
// ---------------------------------------------------------------------------
__global__ __launch_bounds__(256) void k_convert_hist(
        const float* __restrict__ nf, unsigned short* __restrict__ Abuf,
        const int* __restrict__ edges, uint32* __restrict__ deg,
        uint32* __restrict__ rank) {
    int idx = blockIdx.x * 256 + threadIdx.x;          // 0 .. 1.6M
    if (idx < N_NODES * 16) {
        int r = idx >> 4;
        int c = (idx & 15) * 8;
        const float4 v0 = *reinterpret_cast<const float4*>(nf + (size_t)r * D + c);
        const float4 v1 = *reinterpret_cast<const float4*>(nf + (size_t)r * D + c + 4);
        uint4 w;
        w.x = f2bf(v0.x) | (f2bf(v0.y) << 16);
        w.y = f2bf(v0.z) | (f2bf(v0.w) << 16);
        w.z = f2bf(v1.x) | (f2bf(v1.y) << 16);
        w.w = f2bf(v1.z) | (f2bf(v1.w) << 16);
        *reinterpret_cast<uint4*>(Abuf + (size_t)r * 256 + D + c) = w;
    }
    if (idx < N_EDGES) {
        rank[idx] = atomicAdd(&deg[edges[N_EDGES + idx]], 1u);
    }
}

// ---------------------------------------------------------------------------
// Scan phase 1: per-chunk sums. Idle capacity does W-prep + bias fuse.
// WcF chunk c (16B): lane=c&63, f2=c>>6; ks=f2&7, nn=(f2>>3)&3, ch=f2>>5;
//   j = ch*64 + nn*16 + (lane&15); kb = ks*32 + (lane>>4)*8
// ---------------------------------------------------------------------------
__global__ __launch_bounds__(256) void k_scan1(
        const uint32* __restrict__ deg, uint32* __restrict__ partials,
        const float* __restrict__ Wl, const float* __restrict__ Ws,
        const float* __restrict__ bl, const float* __restrict__ bs,
        unsigned short* __restrict__ WcF, float* __restrict__ biasc) {
    const int gidx = blockIdx.x * 256 + threadIdx.x;   // < 50176
    if (gidx < 4096) {
        int lane = gidx & 63, f2 = gidx >> 6;
        int ks = f2 & 7, nn = (f2 >> 3) & 3, ch = f2 >> 5;
        int j = ch * 64 + nn * 16 + (lane & 15);
        int kb = ks * 32 + (lane >> 4) * 8;
        const float* srcp = (kb < D) ? (Wl + (size_t)j * D + kb)
                                     : (Ws + (size_t)j * D + (kb - D));
        const float4 v0 = *reinterpret_cast<const float4*>(srcp);
        const float4 v1 = *reinterpret_cast<const float4*>(srcp + 4);
        uint4 w;
        w.x = f2bf(v0.x) | (f2bf(v0.y) << 16);
        w.y = f2bf(v0.z) | (f2bf(v0.w) << 16);
        w.z = f2bf(v1.x) | (f2bf(v1.y) << 16);
        w.w = f2bf(v1.z) | (f2bf(v1.w) << 16);
        *reinterpret_cast<uint4*>(WcF + (size_t)gidx * 8) = w;
    }
    if (gidx < D) biasc[gidx] = bl[gidx] + bs[gidx];

    __shared__ uint32 s[256];
    const int t = threadIdx.x;
    const int base = blockIdx.x * SCAN_CHUNK;
    uint32 v = 0;
    int i0 = base + t, i1 = base + 256 + t;
    if (i0 < N_NODES) v += deg[i0];
    if (i1 < N_NODES) v += deg[i1];
    s[t] = v;
    __syncthreads();
    for (int d = 128; d > 0; d >>= 1) {
        if (t < d) s[t] += s[t + d];
        __syncthreads();
    }
    if (t == 0) partials[blockIdx.x] = s[0];
}

// ---------------------------------------------------------------------------
// Scan phase 2+3 merged: block base reduced in-block, chunk-local exclusive
// scan -> off only (no cursor needed anymore).
// ---------------------------------------------------------------------------
__global__ __launch_bounds__(256) void k_scan3(
        const uint32* __restrict__ deg, const uint32* __restrict__ partials,
        uint32* __restrict__ off) {
    __shared__ uint32 red[256];
    __shared__ uint32 pair[256];
    const int t = threadIdx.x;
    red[t] = (t < blockIdx.x) ? partials[t] : 0u;     // SCAN_NBLK=196 < 256
    __syncthreads();
    for (int d2 = 128; d2 > 0; d2 >>= 1) {
        if (t < d2) red[t] += red[t + d2];
        __syncthreads();
    }
    const uint32 blockbase = red[0];

    const int i0 = blockIdx.x * SCAN_CHUNK + 2 * t;
    const int i1 = i0 + 1;
    uint32 e0 = (i0 < N_NODES) ? deg[i0] : 0u;
    uint32 e1 = (i1 < N_NODES) ? deg[i1] : 0u;
    pair[t] = e0 + e1;
    __syncthreads();
    for (int d = 1; d < 256; d <<= 1) {
        uint32 add = (t >= d) ? pair[t - d] : 0u;
        __syncthreads();
        pair[t] += add;
        __syncthreads();
    }
    uint32 base = blockbase + ((t > 0) ? pair[t - 1] : 0u);
    if (i0 < N_NODES) off[i0] = base;
    if (i1 < N_NODES) off[i1] = base + e0;
}

// ---------------------------------------------------------------------------
// Bucket-fill via precomputed rank — NO atomics, no dependency chain.
// ---------------------------------------------------------------------------
__global__ __launch_bounds__(256) void k_fill(
        const int* __restrict__ edges, const uint32* __restrict__ off,
        const uint32* __restrict__ rank, uint32* __restrict__ sorted_src) {
    int idx = blockIdx.x * 256 + threadIdx.x;
    if (idx >= N_EDGES) return;
    int src = edges[idx];
    int tgt = edges[N_EDGES + idx];
    sorted_src[off[tgt] + rank[idx]] = (uint32)src;
}

// ---------------------------------------------------------------------------
// Gather-mean: 2 nodes per wave. lane = {g:node, sub:edge parity, cl:16B
// chunk}. One uint4 load instr = one 256B row per 16-lane group (4 rows per
// wave instr); 8-edge unroll per node = 8 independent loads in flight.
// ---------------------------------------------------------------------------
__global__ __launch_bounds__(256) void k_gather(
        const unsigned short* __restrict__ AbufC,
        unsigned short* __restrict__ Abuf,
        const uint32* __restrict__ off, const uint32* __restrict__ deg,
        const uint32* __restrict__ sorted_src) {
    const int wave = threadIdx.x >> 6;
    const int lane = threadIdx.x & 63;
    const int g    = lane >> 5;            // node within the pair
    const int sub  = (lane >> 4) & 1;      // edge parity
    const int cl   = lane & 15;            // 16B column chunk
    const int node = blockIdx.x * 8 + wave * 2 + g;   // grid covers exactly 100000
    const uint32 d = deg[node];
    const uint32 o = off[node];
    const uint32* __restrict__ src = sorted_src + o;

#define LD(s) (*reinterpret_cast<const uint4*>(AbufC + (size_t)(s) * 256 + D + cl * 8))
#define ACC(a, u) { a[0] += bflo(u.x); a[1] += bfhi(u.x); a[2] += bflo(u.y); a[3] += bfhi(u.y); \
                    a[4] += bflo(u.z); a[5] += bfhi(u.z); a[6] += bflo(u.w); a[7] += bfhi(u.w); }

    float aA[8] = {0.f,0.f,0.f,0.f,0.f,0.f,0.f,0.f};
    float aB[8] = {0.f,0.f,0.f,0.f,0.f,0.f,0.f,0.f};
    uint32 j = 0;
    for (; j + 8 <= d; j += 8) {
        uint32 s0 = src[j + 0 + sub];
        uint32 s1 = src[j + 2 + sub];
        uint32 s2 = src[j + 4 + sub];
        uint32 s3 = src[j + 6 + sub];
        uint4 u0 = LD(s0); uint4 u1 = LD(s1); uint4 u2 = LD(s2); uint4 u3 = LD(s3);
        ACC(aA, u0); ACC(aA, u1); ACC(aB, u2); ACC(aB, u3);
    }
    if (j + 4 <= d) {
        uint32 s0 = src[j + 0 + sub];
        uint32 s1 = src[j + 2 + sub];
        uint4 u0 = LD(s0); uint4 u1 = LD(s1);
        ACC(aA, u0); ACC(aA, u1);
        j += 4;
    }
    if (j + 2 <= d) {
        uint32 s0 = src[j + sub];
        uint4 u0 = LD(s0);
        ACC(aA, u0);
        j += 2;
    }
    if (j < d && sub == 0) {
        uint32 s0 = src[j];
        uint4 u0 = LD(s0);
        ACC(aA, u0);
    }
#undef LD
#undef ACC
#pragma unroll
    for (int r = 0; r < 8; ++r) {
        aA[r] += aB[r];
        aA[r] += __shfl_xor(aA[r], 16);    // sub0 + sub1 within the node group
    }
    if (sub == 0) {
        const float inv = 1.0f / (float)(d > 0u ? d : 1u);
        uint4 w;
        w.x = f2bf(aA[0] * inv) | (f2bf(aA[1] * inv) << 16);
        w.y = f2bf(aA[2] * inv) | (f2bf(aA[3] * inv) << 16);
        w.z = f2bf(aA[4] * inv) | (f2bf(aA[5] * inv) << 16);
        w.w = f2bf(aA[6] * inv) | (f2bf(aA[7] * inv) << 16);
        *reinterpret_cast<uint4*>(Abuf + (size_t)node * 256 + cl * 8) = w;
    }
}

// ---------------------------------------------------------------------------
// MFMA GEMM: block = 64 rows x 64 cols (colhalf ch = blockIdx&1), 4 waves of
// 16 rows each. B pre-fragmented in LDS (32 KB): conflict-free ds_read_b128.
// ---------------------------------------------------------------------------
__global__ __launch_bounds__(256) void sage_mfma(
        const unsigned short* __restrict__ Abuf,
        const unsigned short* __restrict__ WcF,
        const float* __restrict__ biasc,
        float* __restrict__ out) {
    __shared__ unsigned short WcL[16384];       // 32 KB = 32 frags x 1 KB
    const int tid = threadIdx.x;
    const int rb = blockIdx.x >> 1;
    const int ch = blockIdx.x & 1;

    const unsigned short* wsrc = WcF + (size_t)ch * 16384;
#pragma unroll
    for (int i = 0; i < 8; ++i) {
        const int o = (i * 256 + tid) * 8;
        *reinterpret_cast<short8*>(&WcL[o]) = *reinterpret_cast<const short8*>(wsrc + o);
    }
    __syncthreads();

    const int wave = tid >> 6;
    const int lane = tid & 63;
    const int lr = lane & 15;
    const int lk = (lane >> 4) * 8;
    const long long row0 = (long long)rb * 64 + wave * 16;

    f32x4 acc[4];
#pragma unroll
    for (int n = 0; n < 4; ++n) acc[n] = (f32x4){0.f, 0.f, 0.f, 0.f};

    const unsigned short* pa = Abuf + (row0 + lr) * 256 + lk;
#pragma unroll
    for (int ks = 0; ks < 8; ++ks) {
        short8 a = *reinterpret_cast<const short8*>(pa + ks * 32);
#pragma unroll
        for (int n = 0; n < 4; ++n) {
            short8 b = *reinterpret_cast<const short8*>(&WcL[((n * 8 + ks) * 64 + lane) * 8]);
            acc[n] = __builtin_amdgcn_mfma_f32_16x16x32_bf16(a, b, acc[n], 0, 0, 0);
        }
    }

    float bv[4];
#pragma unroll
    for (int n = 0; n < 4; ++n) bv[n] = biasc[ch * 64 + n * 16 + lr];

    const int rq = (lane >> 4) * 4;
#pragma unroll
    for (int r = 0; r < 4; ++r) {
        const long long row = row0 + rq + r;
        if (row < N_NODES) {
            float* orow = out + row * D + ch * 64;
#pragma unroll
            for (int n = 0; n < 4; ++n)
                orow[n * 16 + lr] = acc[n][r] + bv[n];
        }
    }
}

extern "C" void kernel_launch(void* const* d_in, const int* in_sizes, int n_in,
                              void* d_out, int out_size, void* d_ws, size_t ws_size,
                              hipStream_t stream) {
    const float* nf    = (const float*)d_in[0];
    const int*   edges = (const int*)d_in[1];
    const float* Wl    = (const float*)d_in[2];
    const float* bl    = (const float*)d_in[3];
    const float* Ws    = (const float*)d_in[4];
    const float* bs    = (const float*)d_in[5];
    float* out = (float*)d_out;

    // workspace layout
    char* p = (char*)d_ws;
    unsigned short* Abuf = (unsigned short*)p; p += (size_t)M_PAD * 256 * sizeof(unsigned short);
    uint32* deg        = (uint32*)p; p += (size_t)N_NODES * sizeof(uint32);
    uint32* off        = (uint32*)p; p += (size_t)N_NODES * sizeof(uint32);
    uint32* rank       = (uint32*)p; p += (size_t)N_EDGES * sizeof(uint32);
    uint32* sorted_src = (uint32*)p; p += (size_t)N_EDGES * sizeof(uint32);
    uint32* partials   = (uint32*)p; p += 1024;
    unsigned short* WcF = (unsigned short*)p; p += (size_t)D * 256 * sizeof(unsigned short);
    float* biasc       = (float*)p;

    k_zero<<<(N_NODES + 255) / 256, 256, 0, stream>>>(deg);
    k_convert_hist<<<(N_NODES * 16 + 255) / 256, 256, 0, stream>>>(nf, Abuf, edges, deg, rank);
    k_scan1<<<SCAN_NBLK, 256, 0, stream>>>(deg, partials, Wl, Ws, bl, bs, WcF, biasc);
    k_scan3<<<SCAN_NBLK, 256, 0, stream>>>(deg, partials, off);
    k_fill<<<(N_EDGES + 255) / 256, 256, 0, stream>>>(edges, off, rank, sorted_src);
    k_gather<<<N_NODES / 8, 256, 0, stream>>>(Abuf, Abuf, off, deg, sorted_src);
    sage_mfma<<<(M_PAD / 64) * 2, 256, 0, stream>>>(Abuf, WcF, biasc, out);
}

// Round 8
// 112.095 us; speedup vs baseline: 10.2643x; 1.0326x over previous
//
#include <hip/hip_runtime.h>

#define N_NODES 100000
#define N_EDGES 600000
#define D 128
#define M_PAD 100096            // 782 * 128

#define SCAN_CHUNK 512
#define SCAN_NBLK ((N_NODES + SCAN_CHUNK - 1) / SCAN_CHUNK)   // 196

typedef unsigned int uint32;
typedef unsigned long long uint64;
typedef __attribute__((ext_vector_type(8))) short short8;
typedef __attribute__((ext_vector_type(4))) float f32x4;

__device__ __forceinline__ uint32 f2bf(float x) {          // RNE f32 -> bf16
    uint32 u = __float_as_uint(x);
    return (u + 0x7FFFu + ((u >> 16) & 1u)) >> 16;
}
__device__ __forceinline__ float bflo(uint32 u) { return __uint_as_float(u << 16); }
__device__ __forceinline__ float bfhi(uint32 u) { return __uint_as_float(u & 0xFFFF0000u); }

// ---------------------------------------------------------------------------
// Zero the degree histogram + scan flags.
// ---------------------------------------------------------------------------
__global__ __launch_bounds__(256) void k_zero(uint32* __restrict__ deg,
                                              uint64* __restrict__ flags) {
    int i = blockIdx.x * 256 + threadIdx.x;
    if (i < N_NODES) deg[i] = 0u;
    if (i < SCAN_NBLK) flags[i] = 0ULL;
}

// ---------------------------------------------------------------------------
// Convert nf -> bf16 upper K-half of Abuf rows; fused degree histogram that
// ALSO records each edge's within-bucket rank (atomicAdd return value).
// ---------------------------------------------------------------------------
__global__ __launch_bounds__(256) void k_convert_hist(
        const float* __restrict__ nf, unsigned short* __restrict__ Abuf,
        const int* __restrict__ edges, uint32* __restrict__ deg,
        uint32* __restrict__ rank) {
    int idx = blockIdx.x * 256 + threadIdx.x;          // 0 .. 1.6M
    if (idx < N_NODES * 16) {
        int r = idx >> 4;
        int c = (idx & 15) * 8;
        const float4 v0 = *reinterpret_cast<const float4*>(nf + (size_t)r * D + c);
        const float4 v1 = *reinterpret_cast<const float4*>(nf + (size_t)r * D + c + 4);
        uint4 w;
        w.x = f2bf(v0.x) | (f2bf(v0.y) << 16);
        w.y = f2bf(v0.z) | (f2bf(v0.w) << 16);
        w.z = f2bf(v1.x) | (f2bf(v1.y) << 16);
        w.w = f2bf(v1.z) | (f2bf(v1.w) << 16);
        *reinterpret_cast<uint4*>(Abuf + (size_t)r * 256 + D + c) = w;
    }
    if (idx < N_EDGES) {
        rank[idx] = atomicAdd(&deg[edges[N_EDGES + idx]], 1u);
    }
}

// ---------------------------------------------------------------------------
// Single-pass scan (merged scan1+scan3): each block publishes its chunk
// aggregate (flag-packed u64), polls all predecessors (196 blocks, all
// co-resident -> deadlock-free), then chunk-local exclusive scan -> off.
// Idle width does W-prep + bias fuse.
// ---------------------------------------------------------------------------
__global__ __launch_bounds__(256) void k_scan(
        const uint32* __restrict__ deg, uint64* __restrict__ flags,
        uint32* __restrict__ off,
        const float* __restrict__ Wl, const float* __restrict__ Ws,
        const float* __restrict__ bl, const float* __restrict__ bs,
        unsigned short* __restrict__ WcF, float* __restrict__ biasc) {
    const int gidx = blockIdx.x * 256 + threadIdx.x;   // < 50176
    if (gidx < 4096) {
        int lane = gidx & 63, f2 = gidx >> 6;
        int ks = f2 & 7, nn = (f2 >> 3) & 3, ch = f2 >> 5;
        int j = ch * 64 + nn * 16 + (lane & 15);
        int kb = ks * 32 + (lane >> 4) * 8;
        const float* srcp = (kb < D) ? (Wl + (size_t)j * D + kb)
                                     : (Ws + (size_t)j * D + (kb - D));
        const float4 v0 = *reinterpret_cast<const float4*>(srcp);
        const float4 v1 = *reinterpret_cast<const float4*>(srcp + 4);
        uint4 w;
        w.x = f2bf(v0.x) | (f2bf(v0.y) << 16);
        w.y = f2bf(v0.z) | (f2bf(v0.w) << 16);
        w.z = f2bf(v1.x) | (f2bf(v1.y) << 16);
        w.w = f2bf(v1.z) | (f2bf(v1.w) << 16);
        *reinterpret_cast<uint4*>(WcF + (size_t)gidx * 8) = w;
    }
    if (gidx < D) biasc[gidx] = bl[gidx] + bs[gidx];

    __shared__ uint32 s[256];
    __shared__ uint32 pair[256];
    const int t = threadIdx.x;
    const int b = blockIdx.x;
    const int i0 = b * SCAN_CHUNK + 2 * t;
    const int i1 = i0 + 1;
    uint32 e0 = (i0 < N_NODES) ? deg[i0] : 0u;
    uint32 e1 = (i1 < N_NODES) ? deg[i1] : 0u;
    pair[t] = e0 + e1;
    s[t] = e0 + e1;
    __syncthreads();
    // block aggregate
    for (int d2 = 128; d2 > 0; d2 >>= 1) {
        if (t < d2) s[t] += s[t + d2];
        __syncthreads();
    }
    if (t == 0) {
        atomicExch(&flags[b], (1ULL << 32) | (uint64)s[0]);   // publish
    }
    // chunk-local inclusive scan
    for (int d = 1; d < 256; d <<= 1) {
        uint32 add = (t >= d) ? pair[t - d] : 0u;
        __syncthreads();
        pair[t] += add;
        __syncthreads();
    }
    // poll predecessors' aggregates
    uint32 agg = 0;
    if (t < b) {                                       // b <= 195 < 256
        uint64 v;
        do { v = atomicAdd(&flags[t], 0ULL); } while ((v >> 32) == 0ULL);
        agg = (uint32)v;
    }
    s[t] = agg;
    __syncthreads();
    for (int d2 = 128; d2 > 0; d2 >>= 1) {
        if (t < d2) s[t] += s[t + d2];
        __syncthreads();
    }
    const uint32 blockbase = s[0];
    uint32 base = blockbase + ((t > 0) ? pair[t - 1] : 0u);
    if (i0 < N_NODES) off[i0] = base;
    if (i1 < N_NODES) off[i1] = base + e0;
}

// ---------------------------------------------------------------------------
// Bucket-fill via precomputed rank — NO atomics, no dependency chain.
// ---------------------------------------------------------------------------
__global__ __launch_bounds__(256) void k_fill(
        const int* __restrict__ edges, const uint32* __restrict__ off,
        const uint32* __restrict__ rank, uint32* __restrict__ sorted_src) {
    int idx = blockIdx.x * 256 + threadIdx.x;
    if (idx >= N_EDGES) return;
    int src = edges[idx];
    int tgt = edges[N_EDGES + idx];
    sorted_src[off[tgt] + rank[idx]] = (uint32)src;
}

// ---------------------------------------------------------------------------
// Gather-mean: 2 nodes per wave, lane = {g:node, sub:edge parity, cl:16B
// chunk}. Main loop: 8 edges/node/iter, 4 independent loads. Tail: ONE
// fully-predicated batch (clamped index + cndmask) = single latency round.
// ---------------------------------------------------------------------------
__global__ __launch_bounds__(256) void k_gather(
        const unsigned short* __restrict__ AbufC,
        unsigned short* __restrict__ Abuf,
        const uint32* __restrict__ off, const uint32* __restrict__ deg,
        const uint32* __restrict__ sorted_src) {
    const int wave = threadIdx.x >> 6;
    const int lane = threadIdx.x & 63;
    const int sub  = (lane >> 4) & 1;      // edge parity
    const int cl   = lane & 15;            // 16B column chunk
    const int node = blockIdx.x * 8 + wave * 2 + (lane >> 5);
    const uint32 d = deg[node];
    const uint32 o = off[node];
    const uint32* __restrict__ src = sorted_src + o;

#define LD(s) (*reinterpret_cast<const uint4*>(AbufC + (size_t)(s) * 256 + D + cl * 8))
#define ACC(a, u) { a[0] += bflo(u.x); a[1] += bfhi(u.x); a[2] += bflo(u.y); a[3] += bfhi(u.y); \
                    a[4] += bflo(u.z); a[5] += bfhi(u.z); a[6] += bflo(u.w); a[7] += bfhi(u.w); }

    float aA[8] = {0.f,0.f,0.f,0.f,0.f,0.f,0.f,0.f};
    float aB[8] = {0.f,0.f,0.f,0.f,0.f,0.f,0.f,0.f};
    uint32 j = 0;
    for (; j + 8 <= d; j += 8) {
        uint32 s0 = src[j + 0 + sub];
        uint32 s1 = src[j + 2 + sub];
        uint32 s2 = src[j + 4 + sub];
        uint32 s3 = src[j + 6 + sub];
        uint4 u0 = LD(s0); uint4 u1 = LD(s1); uint4 u2 = LD(s2); uint4 u3 = LD(s3);
        ACC(aA, u0); ACC(aA, u1); ACC(aB, u2); ACC(aB, u3);
    }
    if (j < d) {                           // <8 edges left: one predicated round
        const uint32 dm1 = d - 1;
        uint32 i0 = j + 0 + sub, i1 = j + 2 + sub, i2 = j + 4 + sub, i3 = j + 6 + sub;
        uint32 s0 = src[i0 < dm1 ? i0 : dm1];
        uint32 s1 = src[i1 < dm1 ? i1 : dm1];
        uint32 s2 = src[i2 < dm1 ? i2 : dm1];
        uint32 s3 = src[i3 < dm1 ? i3 : dm1];
        uint4 u0 = LD(s0); uint4 u1 = LD(s1); uint4 u2 = LD(s2); uint4 u3 = LD(s3);
        if (i0 >= d) { u0.x = 0u; u0.y = 0u; u0.z = 0u; u0.w = 0u; }
        if (i1 >= d) { u1.x = 0u; u1.y = 0u; u1.z = 0u; u1.w = 0u; }
        if (i2 >= d) { u2.x = 0u; u2.y = 0u; u2.z = 0u; u2.w = 0u; }
        if (i3 >= d) { u3.x = 0u; u3.y = 0u; u3.z = 0u; u3.w = 0u; }
        ACC(aA, u0); ACC(aA, u1); ACC(aB, u2); ACC(aB, u3);
    }
#undef LD
#undef ACC
#pragma unroll
    for (int r = 0; r < 8; ++r) {
        aA[r] += aB[r];
        aA[r] += __shfl_xor(aA[r], 16);    // sub0 + sub1 within the node group
    }
    if (sub == 0) {
        const float inv = 1.0f / (float)(d > 0u ? d : 1u);
        uint4 w;
        w.x = f2bf(aA[0] * inv) | (f2bf(aA[1] * inv) << 16);
        w.y = f2bf(aA[2] * inv) | (f2bf(aA[3] * inv) << 16);
        w.z = f2bf(aA[4] * inv) | (f2bf(aA[5] * inv) << 16);
        w.w = f2bf(aA[6] * inv) | (f2bf(aA[7] * inv) << 16);
        *reinterpret_cast<uint4*>(Abuf + (size_t)node * 256 + cl * 8) = w;
    }
}

// ---------------------------------------------------------------------------
// MFMA GEMM: block = 64 rows x 64 cols (colhalf ch = blockIdx&1), 4 waves of
// 16 rows each. B pre-fragmented in LDS (32 KB): conflict-free ds_read_b128.
// ---------------------------------------------------------------------------
__global__ __launch_bounds__(256) void sage_mfma(
        const unsigned short* __restrict__ Abuf,
        const unsigned short* __restrict__ WcF,
        const float* __restrict__ biasc,
        float* __restrict__ out) {
    __shared__ unsigned short WcL[16384];       // 32 KB = 32 frags x 1 KB
    const int tid = threadIdx.x;
    const int rb = blockIdx.x >> 1;
    const int ch = blockIdx.x & 1;

    const unsigned short* wsrc = WcF + (size_t)ch * 16384;
#pragma unroll
    for (int i = 0; i < 8; ++i) {
        const int o = (i * 256 + tid) * 8;
        *reinterpret_cast<short8*>(&WcL[o]) = *reinterpret_cast<const short8*>(wsrc + o);
    }
    __syncthreads();

    const int wave = tid >> 6;
    const int lane = tid & 63;
    const int lr = lane & 15;
    const int lk = (lane >> 4) * 8;
    const long long row0 = (long long)rb * 64 + wave * 16;

    f32x4 acc[4];
#pragma unroll
    for (int n = 0; n < 4; ++n) acc[n] = (f32x4){0.f, 0.f, 0.f, 0.f};

    const unsigned short* pa = Abuf + (row0 + lr) * 256 + lk;
#pragma unroll
    for (int ks = 0; ks < 8; ++ks) {
        short8 a = *reinterpret_cast<const short8*>(pa + ks * 32);
#pragma unroll
        for (int n = 0; n < 4; ++n) {
            short8 b = *reinterpret_cast<const short8*>(&WcL[((n * 8 + ks) * 64 + lane) * 8]);
            acc[n] = __builtin_amdgcn_mfma_f32_16x16x32_bf16(a, b, acc[n], 0, 0, 0);
        }
    }

    float bv[4];
#pragma unroll
    for (int n = 0; n < 4; ++n) bv[n] = biasc[ch * 64 + n * 16 + lr];

    const int rq = (lane >> 4) * 4;
#pragma unroll
    for (int r = 0; r < 4; ++r) {
        const long long row = row0 + rq + r;
        if (row < N_NODES) {
            float* orow = out + row * D + ch * 64;
#pragma unroll
            for (int n = 0; n < 4; ++n)
                orow[n * 16 + lr] = acc[n][r] + bv[n];
        }
    }
}

extern "C" void kernel_launch(void* const* d_in, const int* in_sizes, int n_in,
                              void* d_out, int out_size, void* d_ws, size_t ws_size,
                              hipStream_t stream) {
    const float* nf    = (const float*)d_in[0];
    const int*   edges = (const int*)d_in[1];
    const float* Wl    = (const float*)d_in[2];
    const float* bl    = (const float*)d_in[3];
    const float* Ws    = (const float*)d_in[4];
    const float* bs    = (const float*)d_in[5];
    float* out = (float*)d_out;

    // workspace layout
    char* p = (char*)d_ws;
    unsigned short* Abuf = (unsigned short*)p; p += (size_t)M_PAD * 256 * sizeof(unsigned short);
    uint32* deg        = (uint32*)p; p += (size_t)N_NODES * sizeof(uint32);
    uint32* off        = (uint32*)p; p += (size_t)N_NODES * sizeof(uint32);
    uint32* rank       = (uint32*)p; p += (size_t)N_EDGES * sizeof(uint32);
    uint32* sorted_src = (uint32*)p; p += (size_t)N_EDGES * sizeof(uint32);
    uint64* flags      = (uint64*)p; p += 2048;
    unsigned short* WcF = (unsigned short*)p; p += (size_t)D * 256 * sizeof(unsigned short);
    float* biasc       = (float*)p;

    k_zero<<<(N_NODES + 255) / 256, 256, 0, stream>>>(deg, flags);
    k_convert_hist<<<(N_NODES * 16 + 255) / 256, 256, 0, stream>>>(nf, Abuf, edges, deg, rank);
    k_scan<<<SCAN_NBLK, 256, 0, stream>>>(deg, flags, off, Wl, Ws, bl, bs, WcF, biasc);
    k_fill<<<(N_EDGES + 255) / 256, 256, 0, stream>>>(edges, off, rank, sorted_src);
    k_gather<<<N_NODES / 8, 256, 0, stream>>>(Abuf, Abuf, off, deg, sorted_src);
    sage_mfma<<<(M_PAD / 64) * 2, 256, 0, stream>>>(Abuf, WcF, biasc, out);
}